// Round 2
// baseline (6867.747 us; speedup 1.0000x reference)
//
#include <hip/hip_runtime.h>
#include <cstdint>

#define NV 50257
#define LS 50304   // padded logits row stride (786*64)
#define HD 512
#define G4 2048
#define BS 64
#define TE 256

__device__ __forceinline__ float sigm_f(float x) {
    x = fminf(fmaxf(x, -30.f), 30.f);
    return 1.f / (1.f + __expf(-x));
}
__device__ __forceinline__ float tanh_f(float x) {
    x = fminf(fmaxf(x, -15.f), 15.f);
    float e = __expf(2.f * x);
    return (e - 1.f) / (e + 1.f);
}

// X[t][b][j] = emb_row(t,b) . W_ih[j][:] + b_ih[j] + b_hh[j]
// grid: (nt, 32), block 256. One M-tile = one t (rows = b 0..63), N-tile = 64 j.
__global__ __launch_bounds__(256) void k_x(
    const int* __restrict__ lines, const int* __restrict__ tlines,
    const float* __restrict__ emb_in, const float* __restrict__ emb_tgt,
    const float* __restrict__ W_ih, const float* __restrict__ b_ih,
    const float* __restrict__ b_hh, float* __restrict__ Xbuf, int t0) {
    __shared__ float Ast[32][68];
    __shared__ float Bst[32][68];
    __shared__ const float* rowp[64];
    const int t = t0 + blockIdx.x;
    const int jt = blockIdx.y;
    const int tid = threadIdx.x;
    if (tid < 64) {
        int idx = (t < TE) ? lines[t * BS + tid] : tlines[tid];
        rowp[tid] = ((t < TE) ? emb_in : emb_tgt) + (long)idx * HD;
    }
    __syncthreads();
    const int tx = tid & 15, ty = tid >> 4;
    const int lr = tid >> 2;            // load row 0..63
    const int lc = (tid & 3) * 8;       // load col base in k-chunk
    const float* wrow = W_ih + (long)(jt * 64 + lr) * HD + lc;
    float acc[4][4] = {};
    for (int k0 = 0; k0 < HD; k0 += 32) {
        const float* ar = rowp[lr] + k0 + lc;
        float4 a0 = *(const float4*)ar;
        float4 a1 = *(const float4*)(ar + 4);
        float4 b0 = *(const float4*)(wrow + k0);
        float4 b1 = *(const float4*)(wrow + k0 + 4);
        Ast[lc + 0][lr] = a0.x; Ast[lc + 1][lr] = a0.y;
        Ast[lc + 2][lr] = a0.z; Ast[lc + 3][lr] = a0.w;
        Ast[lc + 4][lr] = a1.x; Ast[lc + 5][lr] = a1.y;
        Ast[lc + 6][lr] = a1.z; Ast[lc + 7][lr] = a1.w;
        Bst[lc + 0][lr] = b0.x; Bst[lc + 1][lr] = b0.y;
        Bst[lc + 2][lr] = b0.z; Bst[lc + 3][lr] = b0.w;
        Bst[lc + 4][lr] = b1.x; Bst[lc + 5][lr] = b1.y;
        Bst[lc + 6][lr] = b1.z; Bst[lc + 7][lr] = b1.w;
        __syncthreads();
#pragma unroll
        for (int kk = 0; kk < 32; kk++) {
            float av[4], bv[4];
            *(float4*)av = *(const float4*)&Ast[kk][ty * 4];
            *(float4*)bv = *(const float4*)&Bst[kk][tx * 4];
#pragma unroll
            for (int i = 0; i < 4; i++)
#pragma unroll
                for (int j = 0; j < 4; j++)
                    acc[i][j] = fmaf(av[i], bv[j], acc[i][j]);
        }
        __syncthreads();
    }
    float* obase = Xbuf + ((long)blockIdx.x * BS) * G4 + jt * 64;
#pragma unroll
    for (int i = 0; i < 4; i++) {
        int r = ty * 4 + i;
        float* orow = obase + (long)r * G4;
#pragma unroll
        for (int j = 0; j < 4; j++) {
            int col = tx * 4 + j;
            int gj = jt * 64 + col;
            orow[col] = acc[i][j] + b_ih[gj] + b_hh[gj];
        }
    }
}

// Monotone-counter grid barrier. All 256 blocks co-resident by capacity
// (256 blocks, 35KB LDS, 256 thr -> >=4 blk/CU possible on 256 CUs).
// Spin is capped: a coherence failure becomes a wrong answer, not a hang.
__device__ __forceinline__ void gbar(int* cnt, int target_cnt) {
    __syncthreads();   // compiler drains vmcnt before s_barrier per wave
    if (threadIdx.x == 0) {
        asm volatile("s_waitcnt vmcnt(0)" ::: "memory");
        __hip_atomic_fetch_add(cnt, 1, __ATOMIC_RELAXED, __HIP_MEMORY_SCOPE_AGENT);
        int guard = 0;
        while (__hip_atomic_load(cnt, __ATOMIC_RELAXED, __HIP_MEMORY_SCOPE_AGENT)
               < target_cnt) {
            __builtin_amdgcn_s_sleep(2);
            if (++guard > 20000) break;   // safety valve
        }
    }
    __syncthreads();
}

// Fused LSTM chunk: nsteps steps from t0 in ONE regular launch.
// grid 256 = 4 b-groups x 64 k-slices, block 256. c carried in registers.
// h exchanged through device-scope (AGENT) atomics -> coherent across XCDs.
__global__ __launch_bounds__(256) void k_steps(
    const float* __restrict__ Xbuf, const float* __restrict__ W_hh,
    float* hs_all, float* c_buf, int* bar, int t0, int nsteps, int bar_base) {
    const int bx = blockIdx.x;
    const int js = bx & 63;     // k-slice: kk base = js*8
    const int bg = bx >> 6;     // b-group
    const int tid = threadIdx.x;
    __shared__ float hl[16][516];       // h[b][k], padded: 2-way-free banks
    __shared__ float g_lds[16][33];

    long cidx = 0;
    float creg = 0.f;
    if (tid < 128) {
        int bb = tid & 15, kk = tid >> 4;           // kk 0..7
        cidx = (long)(bg * 16 + bb) * HD + js * 8 + kk;
        creg = (t0 > 0) ? c_buf[cidx] : 0.f;
    }

    const int b = tid & 15, jj = tid >> 4;
    const int r0 = jj, r1 = jj + 16;
    const long j0 = (long)(r0 >> 3) * HD + js * 8 + (r0 & 7);
    const long j1 = (long)(r1 >> 3) * HD + js * 8 + (r1 & 7);
    const float* w0 = W_hh + j0 * HD;
    const float* w1 = W_hh + j1 * HD;
    const int bglob = bg * 16 + b;

    for (int dt = 0; dt < nsteps; ++dt) {
        const int t = t0 + dt;
        const float* Xt = Xbuf + (long)dt * BS * G4;
        float x0 = Xt[(long)bglob * G4 + j0];
        float x1 = Xt[(long)bglob * G4 + j1];
        float acc0 = 0.f, acc1 = 0.f;
        if (t > 0) {
            const float* hprev = hs_all + (long)(t - 1) * BS * HD + (long)bg * 16 * HD;
#pragma unroll
            for (int m = 0; m < 32; ++m) {
                int idx = m * 256 + tid;            // flat over 16 b x 512 k
                float v = __hip_atomic_load(hprev + idx, __ATOMIC_RELAXED,
                                            __HIP_MEMORY_SCOPE_AGENT);
                hl[idx >> 9][idx & 511] = v;
            }
            __syncthreads();
#pragma unroll 8
            for (int k = 0; k < HD; k += 4) {
                float4 wa = *(const float4*)(w0 + k);
                float4 wb = *(const float4*)(w1 + k);
                float4 hv = *(const float4*)&hl[b][k];
                acc0 = fmaf(hv.x, wa.x, acc0); acc0 = fmaf(hv.y, wa.y, acc0);
                acc0 = fmaf(hv.z, wa.z, acc0); acc0 = fmaf(hv.w, wa.w, acc0);
                acc1 = fmaf(hv.x, wb.x, acc1); acc1 = fmaf(hv.y, wb.y, acc1);
                acc1 = fmaf(hv.z, wb.z, acc1); acc1 = fmaf(hv.w, wb.w, acc1);
            }
        }
        g_lds[b][r0] = x0 + acc0;
        g_lds[b][r1] = x1 + acc1;
        __syncthreads();
        if (tid < 128) {
            int bb = tid & 15, kk = tid >> 4;
            float gi = g_lds[bb][kk];
            float gf = g_lds[bb][8 + kk];
            float gg = g_lds[bb][16 + kk];
            float go = g_lds[bb][24 + kk];
            float iv = sigm_f(gi), fv = sigm_f(gf), gv = tanh_f(gg), ov = sigm_f(go);
            float c_new = fv * creg + iv * gv;
            creg = c_new;
            float h_new = ov * tanh_f(c_new);
            __hip_atomic_store(hs_all + (long)t * BS * HD + cidx, h_new,
                               __ATOMIC_RELAXED, __HIP_MEMORY_SCOPE_AGENT);
        }
        if (dt + 1 < nsteps)
            gbar(bar, (bar_base + dt + 1) * 256);
    }
    if (tid < 128) c_buf[cidx] = creg;
}

// logits[b][v] = hs[b][:] . W_out[v][:] + b_out[v].  grid 786, block 256.
__global__ __launch_bounds__(256) void k_logits(
    const float* __restrict__ hsrow, const float* __restrict__ W_out,
    const float* __restrict__ b_out, float* __restrict__ logits) {
    __shared__ float Ast[32][68];
    __shared__ float Bst[32][68];
    const int v0 = blockIdx.x * 64;
    const int tid = threadIdx.x;
    const int tx = tid & 15, ty = tid >> 4;
    const int lr = tid >> 2;
    const int lc = (tid & 3) * 8;
    int vr = v0 + lr; if (vr > NV - 1) vr = NV - 1;
    const float* arow = hsrow + (long)lr * HD + lc;
    const float* wrow = W_out + (long)vr * HD + lc;
    float acc[4][4] = {};
    for (int k0 = 0; k0 < HD; k0 += 32) {
        float4 a0 = *(const float4*)(arow + k0);
        float4 a1 = *(const float4*)(arow + k0 + 4);
        float4 b0 = *(const float4*)(wrow + k0);
        float4 b1 = *(const float4*)(wrow + k0 + 4);
        Ast[lc + 0][lr] = a0.x; Ast[lc + 1][lr] = a0.y;
        Ast[lc + 2][lr] = a0.z; Ast[lc + 3][lr] = a0.w;
        Ast[lc + 4][lr] = a1.x; Ast[lc + 5][lr] = a1.y;
        Ast[lc + 6][lr] = a1.z; Ast[lc + 7][lr] = a1.w;
        Bst[lc + 0][lr] = b0.x; Bst[lc + 1][lr] = b0.y;
        Bst[lc + 2][lr] = b0.z; Bst[lc + 3][lr] = b0.w;
        Bst[lc + 4][lr] = b1.x; Bst[lc + 5][lr] = b1.y;
        Bst[lc + 6][lr] = b1.z; Bst[lc + 7][lr] = b1.w;
        __syncthreads();
#pragma unroll
        for (int kk = 0; kk < 32; kk++) {
            float av[4], bv[4];
            *(float4*)av = *(const float4*)&Ast[kk][ty * 4];
            *(float4*)bv = *(const float4*)&Bst[kk][tx * 4];
#pragma unroll
            for (int i = 0; i < 4; i++)
#pragma unroll
                for (int j = 0; j < 4; j++)
                    acc[i][j] = fmaf(av[i], bv[j], acc[i][j]);
        }
        __syncthreads();
    }
#pragma unroll
    for (int i = 0; i < 4; i++) {
        int b = ty * 4 + i;
#pragma unroll
        for (int j = 0; j < 4; j++) {
            int v = v0 + tx * 4 + j;
            if (v < NV) logits[(long)b * LS + v] = acc[i][j] + b_out[v];
        }
    }
}

// online logsumexp per batch row. grid 64, block 256.
__global__ __launch_bounds__(256) void k_lse(
    const float* __restrict__ logits, float* __restrict__ lse) {
    const int b = blockIdx.x;
    const float* row = logits + (long)b * LS;
    float m = -1e30f, s = 0.f;
    for (int v = threadIdx.x; v < NV; v += 256) {
        float x = row[v];
        if (x > m) { s = s * __expf(m - x) + 1.f; m = x; }
        else s += __expf(x - m);
    }
    for (int off = 32; off; off >>= 1) {
        float m2 = __shfl_down(m, off);
        float s2 = __shfl_down(s, off);
        float M = fmaxf(m, m2);
        s = s * __expf(m - M) + s2 * __expf(m2 - M);
        m = M;
    }
    __shared__ float ms[4], ss[4];
    int wid = threadIdx.x >> 6, lane = threadIdx.x & 63;
    if (lane == 0) { ms[wid] = m; ss[wid] = s; }
    __syncthreads();
    if (threadIdx.x == 0) {
        m = ms[0]; s = ss[0];
        for (int w = 1; w < 4; w++) {
            float M = fmaxf(m, ms[w]);
            s = s * __expf(m - M) + ss[w] * __expf(ms[w] - M);
            m = M;
        }
        lse[b] = m + __logf(s);
    }
}

__global__ __launch_bounds__(64) void k_loss(
    const float* __restrict__ logits, const float* __restrict__ lse,
    const int* __restrict__ tlines, float* __restrict__ out0) {
    int b = threadIdx.x;
    float v = logits[(long)b * LS + tlines[b]] - lse[b];
    for (int off = 32; off; off >>= 1) v += __shfl_down(v, off);
    if (b == 0) out0[0] = -v * (1.f / 64.f);
}

// partial[tc][h][e] = sum_{t in chunk} exp(ht^T hs_t)[h][e]; also exp_S0.
// grid (64, 4): 8x8 tiles of 64x64 over (h,e), 4 t-chunks of 64. block 256.
__global__ __launch_bounds__(256) void k_attn(
    const float* __restrict__ hs, float* __restrict__ eS0, float* __restrict__ part) {
    __shared__ float Att[64][68];
    __shared__ float Bsm[64][68];
    const int hti = blockIdx.x >> 3, eti = blockIdx.x & 7;
    const int tc = blockIdx.y;
    const int tid = threadIdx.x;
    const int lb = tid >> 2;
    const int lseg = (tid & 3) * 16;
    const float* ht = hs + (long)TE * BS * HD;
    {
        const float* src = ht + (long)lb * HD + hti * 64 + lseg;
#pragma unroll
        for (int m = 0; m < 16; m += 4)
            *(float4*)&Att[lb][lseg + m] = *(const float4*)(src + m);
    }
    const int ti = tid >> 4, tj = tid & 15;
    float ps[4][4] = {};
    for (int dt = 0; dt < 64; dt++) {
        const int t = tc * 64 + dt;
        __syncthreads();
        const float* src = hs + ((long)t * BS + lb) * HD + eti * 64 + lseg;
#pragma unroll
        for (int m = 0; m < 16; m += 4)
            *(float4*)&Bsm[lb][lseg + m] = *(const float4*)(src + m);
        __syncthreads();
        float acc[4][4] = {};
#pragma unroll 4
        for (int b = 0; b < 64; b++) {
            float av[4], bv[4];
            *(float4*)av = *(const float4*)&Att[b][ti * 4];
            *(float4*)bv = *(const float4*)&Bsm[b][tj * 4];
#pragma unroll
            for (int i = 0; i < 4; i++)
#pragma unroll
                for (int j = 0; j < 4; j++)
                    acc[i][j] = fmaf(av[i], bv[j], acc[i][j]);
        }
        const bool first = (tc == 0 && dt == 0);
#pragma unroll
        for (int i = 0; i < 4; i++)
#pragma unroll
            for (int j = 0; j < 4; j++) {
                float e = __expf(acc[i][j]);
                ps[i][j] += e;
                if (first)
                    eS0[(long)(hti * 64 + ti * 4 + i) * HD + eti * 64 + tj * 4 + j] = e;
            }
    }
#pragma unroll
    for (int i = 0; i < 4; i++)
#pragma unroll
        for (int j = 0; j < 4; j++)
            part[(long)tc * 262144 + (long)(hti * 64 + ti * 4 + i) * HD + eti * 64 + tj * 4 + j] = ps[i][j];
}

__global__ __launch_bounds__(256) void k_attn_fin(
    const float* __restrict__ eS0, const float* __restrict__ part,
    float* __restrict__ outat) {
    long i = (long)blockIdx.x * 256 + threadIdx.x;
    float d = part[i] + part[262144 + i] + part[2L * 262144 + i] + part[3L * 262144 + i];
    outat[i] = eS0[i] / d;
}

extern "C" void kernel_launch(void* const* d_in, const int* in_sizes, int n_in,
                              void* d_out, int out_size, void* d_ws, size_t ws_size,
                              hipStream_t stream) {
    (void)in_sizes; (void)n_in; (void)out_size; (void)ws_size;
    const int* input_lines  = (const int*)d_in[0];
    const int* target_lines = (const int*)d_in[1];
    const float* emb_in  = (const float*)d_in[2];
    const float* emb_tgt = (const float*)d_in[3];
    const float* W_ih = (const float*)d_in[4];
    const float* W_hh = (const float*)d_in[5];
    const float* b_ih = (const float*)d_in[6];
    const float* b_hh = (const float*)d_in[7];
    const float* W_out = (const float*)d_in[8];
    const float* b_out = (const float*)d_in[9];
    float* out = (float*)d_out;
    float* ws = (float*)d_ws;

    float* X      = ws;                      // 64*64*2048      = 8388608
    float* hs     = X + 8388608;             // 257*64*512      = 8421376
    float* cbuf   = hs + 8421376;            // 64*512          = 32768
    float* logits = cbuf + 32768;            // 64*50304        = 3219456
    float* lse    = logits + 3219456;        // 64
    float* eS0    = lse + 64;                // 262144
    float* part   = eS0 + 262144;            // 4*262144        = 1048576
    // total ~85.5 MB

    // grid-barrier counter lives in the logits region (unused until k_logits,
    // which runs after all k_steps launches). Zeroed per replay via memset.
    int* bar = (int*)logits;
    hipMemsetAsync(bar, 0, sizeof(int), stream);

    for (int c = 0; c < 4; ++c) {
        hipLaunchKernelGGL(k_x, dim3(64, 32), dim3(256), 0, stream,
                           input_lines, target_lines, emb_in, emb_tgt,
                           W_ih, b_ih, b_hh, X, c * 64);
        hipLaunchKernelGGL(k_steps, dim3(256), dim3(256), 0, stream,
                           X, W_hh, hs, cbuf, bar, c * 64, 64, c * 63);
    }
    // decoder step folded in as t = 256 (x from emb_tgt[tgt0])
    hipLaunchKernelGGL(k_x, dim3(1, 32), dim3(256), 0, stream,
                       input_lines, target_lines, emb_in, emb_tgt,
                       W_ih, b_ih, b_hh, X, 256);
    hipLaunchKernelGGL(k_steps, dim3(256), dim3(256), 0, stream,
                       X, W_hh, hs, cbuf, bar, 256, 1, 0);

    hipLaunchKernelGGL(k_logits, dim3(786), dim3(256), 0, stream,
                       hs + (long)255 * BS * HD, W_out, b_out, logits);
    hipLaunchKernelGGL(k_lse, dim3(64), dim3(256), 0, stream, logits, lse);
    hipLaunchKernelGGL(k_loss, dim3(1), dim3(64), 0, stream,
                       logits, lse, target_lines, out);
    hipLaunchKernelGGL(k_attn, dim3(64, 4), dim3(256), 0, stream, hs, eS0, part);
    hipLaunchKernelGGL(k_attn_fin, dim3(1024), dim3(256), 0, stream, eS0, part, out + 1);
}

// Round 3
// 5399.756 us; speedup vs baseline: 1.2719x; 1.2719x over previous
//
#include <hip/hip_runtime.h>
#include <cstdint>

#define NV 50257
#define LS 50304   // padded logits row stride (786*64)
#define HD 512
#define G4 2048
#define BS 64
#define TE 256

__device__ __forceinline__ float sigm_f(float x) {
    x = fminf(fmaxf(x, -30.f), 30.f);
    return 1.f / (1.f + __expf(-x));
}
__device__ __forceinline__ float tanh_f(float x) {
    x = fminf(fmaxf(x, -15.f), 15.f);
    float e = __expf(2.f * x);
    return (e - 1.f) / (e + 1.f);
}

// X[t][b][j] = emb_row(t,b) . W_ih[j][:] + b_ih[j] + b_hh[j]
// grid: (nt, 32), block 256. One M-tile = one t (rows = b 0..63), N-tile = 64 j.
__global__ __launch_bounds__(256) void k_x(
    const int* __restrict__ lines, const int* __restrict__ tlines,
    const float* __restrict__ emb_in, const float* __restrict__ emb_tgt,
    const float* __restrict__ W_ih, const float* __restrict__ b_ih,
    const float* __restrict__ b_hh, float* __restrict__ Xbuf, int t0) {
    __shared__ float Ast[32][68];
    __shared__ float Bst[32][68];
    __shared__ const float* rowp[64];
    const int t = t0 + blockIdx.x;
    const int jt = blockIdx.y;
    const int tid = threadIdx.x;
    if (tid < 64) {
        int idx = (t < TE) ? lines[t * BS + tid] : tlines[tid];
        rowp[tid] = ((t < TE) ? emb_in : emb_tgt) + (long)idx * HD;
    }
    __syncthreads();
    const int tx = tid & 15, ty = tid >> 4;
    const int lr = tid >> 2;            // load row 0..63
    const int lc = (tid & 3) * 8;       // load col base in k-chunk
    const float* wrow = W_ih + (long)(jt * 64 + lr) * HD + lc;
    float acc[4][4] = {};
    for (int k0 = 0; k0 < HD; k0 += 32) {
        const float* ar = rowp[lr] + k0 + lc;
        float4 a0 = *(const float4*)ar;
        float4 a1 = *(const float4*)(ar + 4);
        float4 b0 = *(const float4*)(wrow + k0);
        float4 b1 = *(const float4*)(wrow + k0 + 4);
        Ast[lc + 0][lr] = a0.x; Ast[lc + 1][lr] = a0.y;
        Ast[lc + 2][lr] = a0.z; Ast[lc + 3][lr] = a0.w;
        Ast[lc + 4][lr] = a1.x; Ast[lc + 5][lr] = a1.y;
        Ast[lc + 6][lr] = a1.z; Ast[lc + 7][lr] = a1.w;
        Bst[lc + 0][lr] = b0.x; Bst[lc + 1][lr] = b0.y;
        Bst[lc + 2][lr] = b0.z; Bst[lc + 3][lr] = b0.w;
        Bst[lc + 4][lr] = b1.x; Bst[lc + 5][lr] = b1.y;
        Bst[lc + 6][lr] = b1.z; Bst[lc + 7][lr] = b1.w;
        __syncthreads();
#pragma unroll
        for (int kk = 0; kk < 32; kk++) {
            float av[4], bv[4];
            *(float4*)av = *(const float4*)&Ast[kk][ty * 4];
            *(float4*)bv = *(const float4*)&Bst[kk][tx * 4];
#pragma unroll
            for (int i = 0; i < 4; i++)
#pragma unroll
                for (int j = 0; j < 4; j++)
                    acc[i][j] = fmaf(av[i], bv[j], acc[i][j]);
        }
        __syncthreads();
    }
    float* obase = Xbuf + ((long)blockIdx.x * BS) * G4 + jt * 64;
#pragma unroll
    for (int i = 0; i < 4; i++) {
        int r = ty * 4 + i;
        float* orow = obase + (long)r * G4;
#pragma unroll
        for (int j = 0; j < 4; j++) {
            int col = tx * 4 + j;
            int gj = jt * 64 + col;
            orow[col] = acc[i][j] + b_ih[gj] + b_hh[gj];
        }
    }
}

// Distributed-flag grid barrier: block i STORES target into flags[i] (no RMW
// contention), thread tid polls flags[tid] (one coalesced load per wave per
// poll). Targets are absolute step numbers -> monotone, no reset race.
// All 256 blocks co-resident by capacity (1 block/CU on 256 CUs).
__device__ __forceinline__ void gbar(int* flags, int target) {
    __syncthreads();   // each wave drains its vmcnt before s_barrier (release)
    if (threadIdx.x == 0)
        __hip_atomic_store(&flags[blockIdx.x], target, __ATOMIC_RELAXED,
                           __HIP_MEMORY_SCOPE_AGENT);
    int guard = 0;
    while (__hip_atomic_load(&flags[threadIdx.x], __ATOMIC_RELAXED,
                             __HIP_MEMORY_SCOPE_AGENT) < target) {
        __builtin_amdgcn_s_sleep(1);
        if (++guard > 2000000) break;   // safety valve: fail loud, not hung
    }
    __syncthreads();
}

// Fused LSTM chunk: nsteps steps from t0 in ONE regular launch.
// grid 256 = 4 b-groups x 64 k-slices, block 256. c carried in registers.
// h exchanged through device-scope (AGENT) atomics -> coherent across XCDs.
__global__ __launch_bounds__(256) void k_steps(
    const float* __restrict__ Xbuf, const float* __restrict__ W_hh,
    float* hs_all, float* c_buf, int* flags, int t0, int nsteps) {
    const int bx = blockIdx.x;
    const int js = bx & 63;     // k-slice: kk base = js*8
    const int bg = bx >> 6;     // b-group
    const int tid = threadIdx.x;
    __shared__ float hl[16][516];       // h[b][k], padded
    __shared__ float g_lds[16][33];

    long cidx = 0;
    float creg = 0.f;
    if (tid < 128) {
        int bb = tid & 15, kk = tid >> 4;           // kk 0..7
        cidx = (long)(bg * 16 + bb) * HD + js * 8 + kk;
        creg = (t0 > 0) ? c_buf[cidx] : 0.f;
    }

    const int b = tid & 15, jj = tid >> 4;
    const int r0 = jj, r1 = jj + 16;
    const long j0 = (long)(r0 >> 3) * HD + js * 8 + (r0 & 7);
    const long j1 = (long)(r1 >> 3) * HD + js * 8 + (r1 & 7);
    const float* w0 = W_hh + j0 * HD;
    const float* w1 = W_hh + j1 * HD;
    const int bglob = bg * 16 + b;

    for (int dt = 0; dt < nsteps; ++dt) {
        const int t = t0 + dt;
        const float* Xt = Xbuf + (long)dt * BS * G4;
        float x0 = Xt[(long)bglob * G4 + j0];
        float x1 = Xt[(long)bglob * G4 + j1];
        float acc0 = 0.f, acc1 = 0.f;
        if (t > 0) {
            const float* hprev = hs_all + (long)(t - 1) * BS * HD + (long)bg * 16 * HD;
            // stage 16b x 512k of h into LDS: 16 coalesced 64-bit coherent loads
            const unsigned long long* hp = (const unsigned long long*)hprev;
#pragma unroll
            for (int m = 0; m < 16; ++m) {
                unsigned long long v = __hip_atomic_load(
                    hp + m * 256 + tid, __ATOMIC_RELAXED, __HIP_MEMORY_SCOPE_AGENT);
                // u64 idx = m*256+tid -> float idx = m*512 + 2*tid -> row m, col 2*tid
                *(float2*)&hl[m][2 * tid - ((tid >> 7) << 8) + ((tid >> 7) << 8)] =
                    *(float2*)&v;
            }
            __syncthreads();
#pragma unroll 8
            for (int k = 0; k < HD; k += 4) {
                float4 wa = *(const float4*)(w0 + k);
                float4 wb = *(const float4*)(w1 + k);
                float4 hv = *(const float4*)&hl[b][k];
                acc0 = fmaf(hv.x, wa.x, acc0); acc0 = fmaf(hv.y, wa.y, acc0);
                acc0 = fmaf(hv.z, wa.z, acc0); acc0 = fmaf(hv.w, wa.w, acc0);
                acc1 = fmaf(hv.x, wb.x, acc1); acc1 = fmaf(hv.y, wb.y, acc1);
                acc1 = fmaf(hv.z, wb.z, acc1); acc1 = fmaf(hv.w, wb.w, acc1);
            }
        }
        g_lds[b][r0] = x0 + acc0;
        g_lds[b][r1] = x1 + acc1;
        __syncthreads();
        if (tid < 128) {
            int bb = tid & 15, kk = tid >> 4;
            float gi = g_lds[bb][kk];
            float gf = g_lds[bb][8 + kk];
            float gg = g_lds[bb][16 + kk];
            float go = g_lds[bb][24 + kk];
            float iv = sigm_f(gi), fv = sigm_f(gf), gv = tanh_f(gg), ov = sigm_f(go);
            float c_new = fv * creg + iv * gv;
            creg = c_new;
            float h_new = ov * tanh_f(c_new);
            __hip_atomic_store(hs_all + (long)t * BS * HD + cidx, h_new,
                               __ATOMIC_RELAXED, __HIP_MEMORY_SCOPE_AGENT);
        }
        if (dt + 1 < nsteps)
            gbar(flags, t + 1);
        else
            __syncthreads();
    }
    if (tid < 128) c_buf[cidx] = creg;
}

// logits[b][v] = hs[b][:] . W_out[v][:] + b_out[v].  grid 786, block 256.
__global__ __launch_bounds__(256) void k_logits(
    const float* __restrict__ hsrow, const float* __restrict__ W_out,
    const float* __restrict__ b_out, float* __restrict__ logits) {
    __shared__ float Ast[32][68];
    __shared__ float Bst[32][68];
    const int v0 = blockIdx.x * 64;
    const int tid = threadIdx.x;
    const int tx = tid & 15, ty = tid >> 4;
    const int lr = tid >> 2;
    const int lc = (tid & 3) * 8;
    int vr = v0 + lr; if (vr > NV - 1) vr = NV - 1;
    const float* arow = hsrow + (long)lr * HD + lc;
    const float* wrow = W_out + (long)vr * HD + lc;
    float acc[4][4] = {};
    for (int k0 = 0; k0 < HD; k0 += 32) {
        float4 a0 = *(const float4*)(arow + k0);
        float4 a1 = *(const float4*)(arow + k0 + 4);
        float4 b0 = *(const float4*)(wrow + k0);
        float4 b1 = *(const float4*)(wrow + k0 + 4);
        Ast[lc + 0][lr] = a0.x; Ast[lc + 1][lr] = a0.y;
        Ast[lc + 2][lr] = a0.z; Ast[lc + 3][lr] = a0.w;
        Ast[lc + 4][lr] = a1.x; Ast[lc + 5][lr] = a1.y;
        Ast[lc + 6][lr] = a1.z; Ast[lc + 7][lr] = a1.w;
        Bst[lc + 0][lr] = b0.x; Bst[lc + 1][lr] = b0.y;
        Bst[lc + 2][lr] = b0.z; Bst[lc + 3][lr] = b0.w;
        Bst[lc + 4][lr] = b1.x; Bst[lc + 5][lr] = b1.y;
        Bst[lc + 6][lr] = b1.z; Bst[lc + 7][lr] = b1.w;
        __syncthreads();
#pragma unroll
        for (int kk = 0; kk < 32; kk++) {
            float av[4], bv[4];
            *(float4*)av = *(const float4*)&Ast[kk][ty * 4];
            *(float4*)bv = *(const float4*)&Bst[kk][tx * 4];
#pragma unroll
            for (int i = 0; i < 4; i++)
#pragma unroll
                for (int j = 0; j < 4; j++)
                    acc[i][j] = fmaf(av[i], bv[j], acc[i][j]);
        }
        __syncthreads();
    }
#pragma unroll
    for (int i = 0; i < 4; i++) {
        int b = ty * 4 + i;
#pragma unroll
        for (int j = 0; j < 4; j++) {
            int v = v0 + tx * 4 + j;
            if (v < NV) logits[(long)b * LS + v] = acc[i][j] + b_out[v];
        }
    }
}

// online logsumexp per batch row. grid 64, block 256.
__global__ __launch_bounds__(256) void k_lse(
    const float* __restrict__ logits, float* __restrict__ lse) {
    const int b = blockIdx.x;
    const float* row = logits + (long)b * LS;
    float m = -1e30f, s = 0.f;
    for (int v = threadIdx.x; v < NV; v += 256) {
        float x = row[v];
        if (x > m) { s = s * __expf(m - x) + 1.f; m = x; }
        else s += __expf(x - m);
    }
    for (int off = 32; off; off >>= 1) {
        float m2 = __shfl_down(m, off);
        float s2 = __shfl_down(s, off);
        float M = fmaxf(m, m2);
        s = s * __expf(m - M) + s2 * __expf(m2 - M);
        m = M;
    }
    __shared__ float ms[4], ss[4];
    int wid = threadIdx.x >> 6, lane = threadIdx.x & 63;
    if (lane == 0) { ms[wid] = m; ss[wid] = s; }
    __syncthreads();
    if (threadIdx.x == 0) {
        m = ms[0]; s = ss[0];
        for (int w = 1; w < 4; w++) {
            float M = fmaxf(m, ms[w]);
            s = s * __expf(m - M) + ss[w] * __expf(ms[w] - M);
            m = M;
        }
        lse[b] = m + __logf(s);
    }
}

__global__ __launch_bounds__(64) void k_loss(
    const float* __restrict__ logits, const float* __restrict__ lse,
    const int* __restrict__ tlines, float* __restrict__ out0) {
    int b = threadIdx.x;
    float v = logits[(long)b * LS + tlines[b]] - lse[b];
    for (int off = 32; off; off >>= 1) v += __shfl_down(v, off);
    if (b == 0) out0[0] = -v * (1.f / 64.f);
}

// partial[tc][h][e] = sum_{t in chunk} exp(ht^T hs_t)[h][e]; also exp_S0.
// grid (64, 4): 8x8 tiles of 64x64 over (h,e), 4 t-chunks of 64. block 256.
__global__ __launch_bounds__(256) void k_attn(
    const float* __restrict__ hs, float* __restrict__ eS0, float* __restrict__ part) {
    __shared__ float Att[64][68];
    __shared__ float Bsm[64][68];
    const int hti = blockIdx.x >> 3, eti = blockIdx.x & 7;
    const int tc = blockIdx.y;
    const int tid = threadIdx.x;
    const int lb = tid >> 2;
    const int lseg = (tid & 3) * 16;
    const float* ht = hs + (long)TE * BS * HD;
    {
        const float* src = ht + (long)lb * HD + hti * 64 + lseg;
#pragma unroll
        for (int m = 0; m < 16; m += 4)
            *(float4*)&Att[lb][lseg + m] = *(const float4*)(src + m);
    }
    const int ti = tid >> 4, tj = tid & 15;
    float ps[4][4] = {};
    for (int dt = 0; dt < 64; dt++) {
        const int t = tc * 64 + dt;
        __syncthreads();
        const float* src = hs + ((long)t * BS + lb) * HD + eti * 64 + lseg;
#pragma unroll
        for (int m = 0; m < 16; m += 4)
            *(float4*)&Bsm[lb][lseg + m] = *(const float4*)(src + m);
        __syncthreads();
        float acc[4][4] = {};
#pragma unroll 4
        for (int b = 0; b < 64; b++) {
            float av[4], bv[4];
            *(float4*)av = *(const float4*)&Att[b][ti * 4];
            *(float4*)bv = *(const float4*)&Bsm[b][tj * 4];
#pragma unroll
            for (int i = 0; i < 4; i++)
#pragma unroll
                for (int j = 0; j < 4; j++)
                    acc[i][j] = fmaf(av[i], bv[j], acc[i][j]);
        }
        const bool first = (tc == 0 && dt == 0);
#pragma unroll
        for (int i = 0; i < 4; i++)
#pragma unroll
            for (int j = 0; j < 4; j++) {
                float e = __expf(acc[i][j]);
                ps[i][j] += e;
                if (first)
                    eS0[(long)(hti * 64 + ti * 4 + i) * HD + eti * 64 + tj * 4 + j] = e;
            }
    }
#pragma unroll
    for (int i = 0; i < 4; i++)
#pragma unroll
        for (int j = 0; j < 4; j++)
            part[(long)tc * 262144 + (long)(hti * 64 + ti * 4 + i) * HD + eti * 64 + tj * 4 + j] = ps[i][j];
}

__global__ __launch_bounds__(256) void k_attn_fin(
    const float* __restrict__ eS0, const float* __restrict__ part,
    float* __restrict__ outat) {
    long i = (long)blockIdx.x * 256 + threadIdx.x;
    float d = part[i] + part[262144 + i] + part[2L * 262144 + i] + part[3L * 262144 + i];
    outat[i] = eS0[i] / d;
}

extern "C" void kernel_launch(void* const* d_in, const int* in_sizes, int n_in,
                              void* d_out, int out_size, void* d_ws, size_t ws_size,
                              hipStream_t stream) {
    (void)in_sizes; (void)n_in; (void)out_size; (void)ws_size;
    const int* input_lines  = (const int*)d_in[0];
    const int* target_lines = (const int*)d_in[1];
    const float* emb_in  = (const float*)d_in[2];
    const float* emb_tgt = (const float*)d_in[3];
    const float* W_ih = (const float*)d_in[4];
    const float* W_hh = (const float*)d_in[5];
    const float* b_ih = (const float*)d_in[6];
    const float* b_hh = (const float*)d_in[7];
    const float* W_out = (const float*)d_in[8];
    const float* b_out = (const float*)d_in[9];
    float* out = (float*)d_out;
    float* ws = (float*)d_ws;

    float* X      = ws;                      // 64*64*2048      = 8388608
    float* hs     = X + 8388608;             // 257*64*512      = 8421376
    float* cbuf   = hs + 8421376;            // 64*512          = 32768
    float* logits = cbuf + 32768;            // 64*50304        = 3219456
    float* lse    = logits + 3219456;        // 64
    float* eS0    = lse + 64;                // 262144
    float* part   = eS0 + 262144;            // 4*262144        = 1048576
    // total ~85.5 MB

    // barrier flags (256 ints) live in the logits region (unused until
    // k_logits, which runs after all k_steps). Zeroed per replay.
    int* flags = (int*)logits;
    hipMemsetAsync(flags, 0, 256 * sizeof(int), stream);

    for (int c = 0; c < 4; ++c) {
        hipLaunchKernelGGL(k_x, dim3(64, 32), dim3(256), 0, stream,
                           input_lines, target_lines, emb_in, emb_tgt,
                           W_ih, b_ih, b_hh, X, c * 64);
        hipLaunchKernelGGL(k_steps, dim3(256), dim3(256), 0, stream,
                           X, W_hh, hs, cbuf, flags, c * 64, 64);
    }
    // decoder step folded in as t = 256 (x from emb_tgt[tgt0])
    hipLaunchKernelGGL(k_x, dim3(1, 32), dim3(256), 0, stream,
                       input_lines, target_lines, emb_in, emb_tgt,
                       W_ih, b_ih, b_hh, X, 256);
    hipLaunchKernelGGL(k_steps, dim3(256), dim3(256), 0, stream,
                       X, W_hh, hs, cbuf, flags, 256, 1);

    hipLaunchKernelGGL(k_logits, dim3(786), dim3(256), 0, stream,
                       hs + (long)255 * BS * HD, W_out, b_out, logits);
    hipLaunchKernelGGL(k_lse, dim3(64), dim3(256), 0, stream, logits, lse);
    hipLaunchKernelGGL(k_loss, dim3(1), dim3(64), 0, stream,
                       logits, lse, target_lines, out);
    hipLaunchKernelGGL(k_attn, dim3(64, 4), dim3(256), 0, stream, hs, eS0, part);
    hipLaunchKernelGGL(k_attn_fin, dim3(1024), dim3(256), 0, stream, eS0, part, out + 1);
}

// Round 4
// 4640.416 us; speedup vs baseline: 1.4800x; 1.1636x over previous
//
#include <hip/hip_runtime.h>
#include <cstdint>

#define NV 50257
#define LS 50304   // padded logits row stride (786*64)
#define HD 512
#define G4 2048
#define BS 64
#define TE 256

__device__ __forceinline__ float sigm_f(float x) {
    x = fminf(fmaxf(x, -30.f), 30.f);
    return 1.f / (1.f + __expf(-x));
}
__device__ __forceinline__ float tanh_f(float x) {
    x = fminf(fmaxf(x, -15.f), 15.f);
    float e = __expf(2.f * x);
    return (e - 1.f) / (e + 1.f);
}

// X[t][b][j] = emb_row(t,b) . W_ih[j][:] + b_ih[j] + b_hh[j]
// grid: (nt, 32), block 256. One M-tile = one t (rows = b 0..63), N-tile = 64 j.
__global__ __launch_bounds__(256) void k_x(
    const int* __restrict__ lines, const int* __restrict__ tlines,
    const float* __restrict__ emb_in, const float* __restrict__ emb_tgt,
    const float* __restrict__ W_ih, const float* __restrict__ b_ih,
    const float* __restrict__ b_hh, float* __restrict__ Xbuf, int t0) {
    __shared__ float Ast[32][68];
    __shared__ float Bst[32][68];
    __shared__ const float* rowp[64];
    const int t = t0 + blockIdx.x;
    const int jt = blockIdx.y;
    const int tid = threadIdx.x;
    if (tid < 64) {
        int idx = (t < TE) ? lines[t * BS + tid] : tlines[tid];
        rowp[tid] = ((t < TE) ? emb_in : emb_tgt) + (long)idx * HD;
    }
    __syncthreads();
    const int tx = tid & 15, ty = tid >> 4;
    const int lr = tid >> 2;            // load row 0..63
    const int lc = (tid & 3) * 8;       // load col base in k-chunk
    const float* wrow = W_ih + (long)(jt * 64 + lr) * HD + lc;
    float acc[4][4] = {};
    for (int k0 = 0; k0 < HD; k0 += 32) {
        const float* ar = rowp[lr] + k0 + lc;
        float4 a0 = *(const float4*)ar;
        float4 a1 = *(const float4*)(ar + 4);
        float4 b0 = *(const float4*)(wrow + k0);
        float4 b1 = *(const float4*)(wrow + k0 + 4);
        Ast[lc + 0][lr] = a0.x; Ast[lc + 1][lr] = a0.y;
        Ast[lc + 2][lr] = a0.z; Ast[lc + 3][lr] = a0.w;
        Ast[lc + 4][lr] = a1.x; Ast[lc + 5][lr] = a1.y;
        Ast[lc + 6][lr] = a1.z; Ast[lc + 7][lr] = a1.w;
        Bst[lc + 0][lr] = b0.x; Bst[lc + 1][lr] = b0.y;
        Bst[lc + 2][lr] = b0.z; Bst[lc + 3][lr] = b0.w;
        Bst[lc + 4][lr] = b1.x; Bst[lc + 5][lr] = b1.y;
        Bst[lc + 6][lr] = b1.z; Bst[lc + 7][lr] = b1.w;
        __syncthreads();
#pragma unroll
        for (int kk = 0; kk < 32; kk++) {
            float av[4], bv[4];
            *(float4*)av = *(const float4*)&Ast[kk][ty * 4];
            *(float4*)bv = *(const float4*)&Bst[kk][tx * 4];
#pragma unroll
            for (int i = 0; i < 4; i++)
#pragma unroll
                for (int j = 0; j < 4; j++)
                    acc[i][j] = fmaf(av[i], bv[j], acc[i][j]);
        }
        __syncthreads();
    }
    float* obase = Xbuf + ((long)blockIdx.x * BS) * G4 + jt * 64;
#pragma unroll
    for (int i = 0; i < 4; i++) {
        int r = ty * 4 + i;
        float* orow = obase + (long)r * G4;
#pragma unroll
        for (int j = 0; j < 4; j++) {
            int col = tx * 4 + j;
            int gj = jt * 64 + col;
            orow[col] = acc[i][j] + b_ih[gj] + b_hh[gj];
        }
    }
}

// bg-local grid barrier: only the 64 blocks sharing bg (which exchange h)
// participate. Block stores flags[bx] = target (no RMW); wave 0 polls one
// flag per lane; waves 1-3 wait at s_barrier. Targets are absolute step
// numbers -> monotone, no reset race. Group flag region = 256B, line-disjoint.
__device__ __forceinline__ void gbar(int* flags, int bx, int bg, int target) {
    __syncthreads();   // each wave drains its vmcnt before s_barrier (release)
    if (threadIdx.x == 0)
        __hip_atomic_store(&flags[bx], target, __ATOMIC_RELAXED,
                           __HIP_MEMORY_SCOPE_AGENT);
    if (threadIdx.x < 64) {
        int guard = 0;
        while (__hip_atomic_load(&flags[bg * 64 + threadIdx.x], __ATOMIC_RELAXED,
                                 __HIP_MEMORY_SCOPE_AGENT) < target) {
            __builtin_amdgcn_s_sleep(1);
            if (++guard > 2000000) break;   // safety valve: fail loud, not hung
        }
    }
    __syncthreads();
}

// Fused LSTM chunk: nsteps steps from t0 in ONE regular launch.
// grid 256 = 4 b-groups x 64 k-slices, block 256. c carried in registers.
// h exchanged through device-scope (AGENT) atomics -> coherent across XCDs.
__global__ __launch_bounds__(256) void k_steps(
    const float* __restrict__ Xbuf, const float* __restrict__ W_hh,
    float* hs_all, float* c_buf, int* flags, int t0, int nsteps) {
    const int bx = blockIdx.x;
    const int js = bx & 63;     // k-slice: kk base = js*8
    const int bg = bx >> 6;     // b-group
    const int tid = threadIdx.x;
    __shared__ float hl[16][516];       // h[b][k], padded
    __shared__ float g_lds[16][33];

    long cidx = 0;
    float creg = 0.f;
    if (tid < 128) {
        int bb = tid & 15, kk = tid >> 4;           // kk 0..7
        cidx = (long)(bg * 16 + bb) * HD + js * 8 + kk;
        creg = (t0 > 0) ? c_buf[cidx] : 0.f;
    }

    const int b = tid & 15, jj = tid >> 4;
    const int r0 = jj, r1 = jj + 16;
    const long j0 = (long)(r0 >> 3) * HD + js * 8 + (r0 & 7);
    const long j1 = (long)(r1 >> 3) * HD + js * 8 + (r1 & 7);
    const float* w0 = W_hh + j0 * HD;
    const float* w1 = W_hh + j1 * HD;
    const int bglob = bg * 16 + b;

    // prefetch X for the first step (later steps prefetch before the barrier)
    float x0 = Xbuf[(long)bglob * G4 + j0];
    float x1 = Xbuf[(long)bglob * G4 + j1];

    for (int dt = 0; dt < nsteps; ++dt) {
        const int t = t0 + dt;
        float acc0 = 0.f, acc1 = 0.f;
        if (t > 0) {
            const float* hprev = hs_all + (long)(t - 1) * BS * HD + (long)bg * 16 * HD;
            const unsigned long long* hp = (const unsigned long long*)hprev;
            // stage 16b x 512k of h: issue ALL 16 coherent loads into regs
            // first (one latency), then bulk-write LDS.
            unsigned long long tmp[16];
#pragma unroll
            for (int m = 0; m < 16; ++m)
                tmp[m] = __hip_atomic_load(hp + m * 256 + tid, __ATOMIC_RELAXED,
                                           __HIP_MEMORY_SCOPE_AGENT);
#pragma unroll
            for (int m = 0; m < 16; ++m)
                *(float2*)&hl[m][2 * tid] = *(float2*)&tmp[m];
            __syncthreads();
#pragma unroll 8
            for (int k = 0; k < HD; k += 4) {
                float4 wa = *(const float4*)(w0 + k);
                float4 wb = *(const float4*)(w1 + k);
                float4 hv = *(const float4*)&hl[b][k];
                acc0 = fmaf(hv.x, wa.x, acc0); acc0 = fmaf(hv.y, wa.y, acc0);
                acc0 = fmaf(hv.z, wa.z, acc0); acc0 = fmaf(hv.w, wa.w, acc0);
                acc1 = fmaf(hv.x, wb.x, acc1); acc1 = fmaf(hv.y, wb.y, acc1);
                acc1 = fmaf(hv.z, wb.z, acc1); acc1 = fmaf(hv.w, wb.w, acc1);
            }
        }
        g_lds[b][r0] = x0 + acc0;
        g_lds[b][r1] = x1 + acc1;
        __syncthreads();
        if (tid < 128) {
            int bb = tid & 15, kk = tid >> 4;
            float gi = g_lds[bb][kk];
            float gf = g_lds[bb][8 + kk];
            float gg = g_lds[bb][16 + kk];
            float go = g_lds[bb][24 + kk];
            float iv = sigm_f(gi), fv = sigm_f(gf), gv = tanh_f(gg), ov = sigm_f(go);
            float c_new = fv * creg + iv * gv;
            creg = c_new;
            float h_new = ov * tanh_f(c_new);
            __hip_atomic_store(hs_all + (long)t * BS * HD + cidx, h_new,
                               __ATOMIC_RELAXED, __HIP_MEMORY_SCOPE_AGENT);
        }
        if (dt + 1 < nsteps) {
            // prefetch next step's X before the barrier (hidden under poll)
            const float* Xn = Xbuf + (long)(dt + 1) * BS * G4;
            x0 = Xn[(long)bglob * G4 + j0];
            x1 = Xn[(long)bglob * G4 + j1];
            gbar(flags, bx, bg, t + 1);
        } else {
            __syncthreads();
        }
    }
    if (tid < 128) c_buf[cidx] = creg;
}

// logits[b][v] = hs[b][:] . W_out[v][:] + b_out[v].  grid 786, block 256.
__global__ __launch_bounds__(256) void k_logits(
    const float* __restrict__ hsrow, const float* __restrict__ W_out,
    const float* __restrict__ b_out, float* __restrict__ logits) {
    __shared__ float Ast[32][68];
    __shared__ float Bst[32][68];
    const int v0 = blockIdx.x * 64;
    const int tid = threadIdx.x;
    const int tx = tid & 15, ty = tid >> 4;
    const int lr = tid >> 2;
    const int lc = (tid & 3) * 8;
    int vr = v0 + lr; if (vr > NV - 1) vr = NV - 1;
    const float* arow = hsrow + (long)lr * HD + lc;
    const float* wrow = W_out + (long)vr * HD + lc;
    float acc[4][4] = {};
    for (int k0 = 0; k0 < HD; k0 += 32) {
        float4 a0 = *(const float4*)(arow + k0);
        float4 a1 = *(const float4*)(arow + k0 + 4);
        float4 b0 = *(const float4*)(wrow + k0);
        float4 b1 = *(const float4*)(wrow + k0 + 4);
        Ast[lc + 0][lr] = a0.x; Ast[lc + 1][lr] = a0.y;
        Ast[lc + 2][lr] = a0.z; Ast[lc + 3][lr] = a0.w;
        Ast[lc + 4][lr] = a1.x; Ast[lc + 5][lr] = a1.y;
        Ast[lc + 6][lr] = a1.z; Ast[lc + 7][lr] = a1.w;
        Bst[lc + 0][lr] = b0.x; Bst[lc + 1][lr] = b0.y;
        Bst[lc + 2][lr] = b0.z; Bst[lc + 3][lr] = b0.w;
        Bst[lc + 4][lr] = b1.x; Bst[lc + 5][lr] = b1.y;
        Bst[lc + 6][lr] = b1.z; Bst[lc + 7][lr] = b1.w;
        __syncthreads();
#pragma unroll
        for (int kk = 0; kk < 32; kk++) {
            float av[4], bv[4];
            *(float4*)av = *(const float4*)&Ast[kk][ty * 4];
            *(float4*)bv = *(const float4*)&Bst[kk][tx * 4];
#pragma unroll
            for (int i = 0; i < 4; i++)
#pragma unroll
                for (int j = 0; j < 4; j++)
                    acc[i][j] = fmaf(av[i], bv[j], acc[i][j]);
        }
        __syncthreads();
    }
#pragma unroll
    for (int i = 0; i < 4; i++) {
        int b = ty * 4 + i;
#pragma unroll
        for (int j = 0; j < 4; j++) {
            int v = v0 + tx * 4 + j;
            if (v < NV) logits[(long)b * LS + v] = acc[i][j] + b_out[v];
        }
    }
}

// online logsumexp per batch row. grid 64, block 256.
__global__ __launch_bounds__(256) void k_lse(
    const float* __restrict__ logits, float* __restrict__ lse) {
    const int b = blockIdx.x;
    const float* row = logits + (long)b * LS;
    float m = -1e30f, s = 0.f;
    for (int v = threadIdx.x; v < NV; v += 256) {
        float x = row[v];
        if (x > m) { s = s * __expf(m - x) + 1.f; m = x; }
        else s += __expf(x - m);
    }
    for (int off = 32; off; off >>= 1) {
        float m2 = __shfl_down(m, off);
        float s2 = __shfl_down(s, off);
        float M = fmaxf(m, m2);
        s = s * __expf(m - M) + s2 * __expf(m2 - M);
        m = M;
    }
    __shared__ float ms[4], ss[4];
    int wid = threadIdx.x >> 6, lane = threadIdx.x & 63;
    if (lane == 0) { ms[wid] = m; ss[wid] = s; }
    __syncthreads();
    if (threadIdx.x == 0) {
        m = ms[0]; s = ss[0];
        for (int w = 1; w < 4; w++) {
            float M = fmaxf(m, ms[w]);
            s = s * __expf(m - M) + ss[w] * __expf(ms[w] - M);
            m = M;
        }
        lse[b] = m + __logf(s);
    }
}

__global__ __launch_bounds__(64) void k_loss(
    const float* __restrict__ logits, const float* __restrict__ lse,
    const int* __restrict__ tlines, float* __restrict__ out0) {
    int b = threadIdx.x;
    float v = logits[(long)b * LS + tlines[b]] - lse[b];
    for (int off = 32; off; off >>= 1) v += __shfl_down(v, off);
    if (b == 0) out0[0] = -v * (1.f / 64.f);
}

// partial[tc][h][e] = sum_{t in chunk} exp(ht^T hs_t)[h][e]; also exp_S0.
// grid (64, 4): 8x8 tiles of 64x64 over (h,e), 4 t-chunks of 64. block 256.
__global__ __launch_bounds__(256) void k_attn(
    const float* __restrict__ hs, float* __restrict__ eS0, float* __restrict__ part) {
    __shared__ float Att[64][68];
    __shared__ float Bsm[64][68];
    const int hti = blockIdx.x >> 3, eti = blockIdx.x & 7;
    const int tc = blockIdx.y;
    const int tid = threadIdx.x;
    const int lb = tid >> 2;
    const int lseg = (tid & 3) * 16;
    const float* ht = hs + (long)TE * BS * HD;
    {
        const float* src = ht + (long)lb * HD + hti * 64 + lseg;
#pragma unroll
        for (int m = 0; m < 16; m += 4)
            *(float4*)&Att[lb][lseg + m] = *(const float4*)(src + m);
    }
    const int ti = tid >> 4, tj = tid & 15;
    float ps[4][4] = {};
    for (int dt = 0; dt < 64; dt++) {
        const int t = tc * 64 + dt;
        __syncthreads();
        const float* src = hs + ((long)t * BS + lb) * HD + eti * 64 + lseg;
#pragma unroll
        for (int m = 0; m < 16; m += 4)
            *(float4*)&Bsm[lb][lseg + m] = *(const float4*)(src + m);
        __syncthreads();
        float acc[4][4] = {};
#pragma unroll 4
        for (int b = 0; b < 64; b++) {
            float av[4], bv[4];
            *(float4*)av = *(const float4*)&Att[b][ti * 4];
            *(float4*)bv = *(const float4*)&Bsm[b][tj * 4];
#pragma unroll
            for (int i = 0; i < 4; i++)
#pragma unroll
                for (int j = 0; j < 4; j++)
                    acc[i][j] = fmaf(av[i], bv[j], acc[i][j]);
        }
        const bool first = (tc == 0 && dt == 0);
#pragma unroll
        for (int i = 0; i < 4; i++)
#pragma unroll
            for (int j = 0; j < 4; j++) {
                float e = __expf(acc[i][j]);
                ps[i][j] += e;
                if (first)
                    eS0[(long)(hti * 64 + ti * 4 + i) * HD + eti * 64 + tj * 4 + j] = e;
            }
    }
#pragma unroll
    for (int i = 0; i < 4; i++)
#pragma unroll
        for (int j = 0; j < 4; j++)
            part[(long)tc * 262144 + (long)(hti * 64 + ti * 4 + i) * HD + eti * 64 + tj * 4 + j] = ps[i][j];
}

__global__ __launch_bounds__(256) void k_attn_fin(
    const float* __restrict__ eS0, const float* __restrict__ part,
    float* __restrict__ outat) {
    long i = (long)blockIdx.x * 256 + threadIdx.x;
    float d = part[i] + part[262144 + i] + part[2L * 262144 + i] + part[3L * 262144 + i];
    outat[i] = eS0[i] / d;
}

extern "C" void kernel_launch(void* const* d_in, const int* in_sizes, int n_in,
                              void* d_out, int out_size, void* d_ws, size_t ws_size,
                              hipStream_t stream) {
    (void)in_sizes; (void)n_in; (void)out_size; (void)ws_size;
    const int* input_lines  = (const int*)d_in[0];
    const int* target_lines = (const int*)d_in[1];
    const float* emb_in  = (const float*)d_in[2];
    const float* emb_tgt = (const float*)d_in[3];
    const float* W_ih = (const float*)d_in[4];
    const float* W_hh = (const float*)d_in[5];
    const float* b_ih = (const float*)d_in[6];
    const float* b_hh = (const float*)d_in[7];
    const float* W_out = (const float*)d_in[8];
    const float* b_out = (const float*)d_in[9];
    float* out = (float*)d_out;
    float* ws = (float*)d_ws;

    float* X      = ws;                      // 64*64*2048      = 8388608
    float* hs     = X + 8388608;             // 257*64*512      = 8421376
    float* cbuf   = hs + 8421376;            // 64*512          = 32768
    float* logits = cbuf + 32768;            // 64*50304        = 3219456
    float* lse    = logits + 3219456;        // 64
    float* eS0    = lse + 64;                // 262144
    float* part   = eS0 + 262144;            // 4*262144        = 1048576
    // total ~85.5 MB

    // barrier flags (256 ints) live in the logits region (unused until
    // k_logits, which runs after all k_steps). Zeroed per replay.
    int* flags = (int*)logits;
    hipMemsetAsync(flags, 0, 256 * sizeof(int), stream);

    for (int c = 0; c < 4; ++c) {
        hipLaunchKernelGGL(k_x, dim3(64, 32), dim3(256), 0, stream,
                           input_lines, target_lines, emb_in, emb_tgt,
                           W_ih, b_ih, b_hh, X, c * 64);
        hipLaunchKernelGGL(k_steps, dim3(256), dim3(256), 0, stream,
                           X, W_hh, hs, cbuf, flags, c * 64, 64);
    }
    // decoder step folded in as t = 256 (x from emb_tgt[tgt0])
    hipLaunchKernelGGL(k_x, dim3(1, 32), dim3(256), 0, stream,
                       input_lines, target_lines, emb_in, emb_tgt,
                       W_ih, b_ih, b_hh, X, 256);
    hipLaunchKernelGGL(k_steps, dim3(256), dim3(256), 0, stream,
                       X, W_hh, hs, cbuf, flags, 256, 1);

    hipLaunchKernelGGL(k_logits, dim3(786), dim3(256), 0, stream,
                       hs + (long)255 * BS * HD, W_out, b_out, logits);
    hipLaunchKernelGGL(k_lse, dim3(64), dim3(256), 0, stream, logits, lse);
    hipLaunchKernelGGL(k_loss, dim3(1), dim3(64), 0, stream,
                       logits, lse, target_lines, out);
    hipLaunchKernelGGL(k_attn, dim3(64, 4), dim3(256), 0, stream, hs, eS0, part);
    hipLaunchKernelGGL(k_attn_fin, dim3(1024), dim3(256), 0, stream, eS0, part, out + 1);
}

// Round 5
// 3315.266 us; speedup vs baseline: 2.0716x; 1.3997x over previous
//
#include <hip/hip_runtime.h>
#include <cstdint>

#define NV 50257
#define LS 50304   // padded logits row stride (786*64)
#define HD 512
#define G4 2048
#define BS 64
#define TE 256

__device__ __forceinline__ float sigm_f(float x) {
    x = fminf(fmaxf(x, -30.f), 30.f);
    return 1.f / (1.f + __expf(-x));
}
__device__ __forceinline__ float tanh_f(float x) {
    x = fminf(fmaxf(x, -15.f), 15.f);
    float e = __expf(2.f * x);
    return (e - 1.f) / (e + 1.f);
}

// X[t][b][j] = emb_row(t,b) . W_ih[j][:] + b_ih[j] + b_hh[j]
// grid: (nt, 32), block 256. One M-tile = one t (rows = b 0..63), N-tile = 64 j.
__global__ __launch_bounds__(256) void k_x(
    const int* __restrict__ lines, const int* __restrict__ tlines,
    const float* __restrict__ emb_in, const float* __restrict__ emb_tgt,
    const float* __restrict__ W_ih, const float* __restrict__ b_ih,
    const float* __restrict__ b_hh, float* __restrict__ Xbuf, int t0) {
    __shared__ float Ast[32][68];
    __shared__ float Bst[32][68];
    __shared__ const float* rowp[64];
    const int t = t0 + blockIdx.x;
    const int jt = blockIdx.y;
    const int tid = threadIdx.x;
    if (tid < 64) {
        int idx = (t < TE) ? lines[t * BS + tid] : tlines[tid];
        rowp[tid] = ((t < TE) ? emb_in : emb_tgt) + (long)idx * HD;
    }
    __syncthreads();
    const int tx = tid & 15, ty = tid >> 4;
    const int lr = tid >> 2;            // load row 0..63
    const int lc = (tid & 3) * 8;       // load col base in k-chunk
    const float* wrow = W_ih + (long)(jt * 64 + lr) * HD + lc;
    float acc[4][4] = {};
    for (int k0 = 0; k0 < HD; k0 += 32) {
        const float* ar = rowp[lr] + k0 + lc;
        float4 a0 = *(const float4*)ar;
        float4 a1 = *(const float4*)(ar + 4);
        float4 b0 = *(const float4*)(wrow + k0);
        float4 b1 = *(const float4*)(wrow + k0 + 4);
        Ast[lc + 0][lr] = a0.x; Ast[lc + 1][lr] = a0.y;
        Ast[lc + 2][lr] = a0.z; Ast[lc + 3][lr] = a0.w;
        Ast[lc + 4][lr] = a1.x; Ast[lc + 5][lr] = a1.y;
        Ast[lc + 6][lr] = a1.z; Ast[lc + 7][lr] = a1.w;
        Bst[lc + 0][lr] = b0.x; Bst[lc + 1][lr] = b0.y;
        Bst[lc + 2][lr] = b0.z; Bst[lc + 3][lr] = b0.w;
        Bst[lc + 4][lr] = b1.x; Bst[lc + 5][lr] = b1.y;
        Bst[lc + 6][lr] = b1.z; Bst[lc + 7][lr] = b1.w;
        __syncthreads();
#pragma unroll
        for (int kk = 0; kk < 32; kk++) {
            float av[4], bv[4];
            *(float4*)av = *(const float4*)&Ast[kk][ty * 4];
            *(float4*)bv = *(const float4*)&Bst[kk][tx * 4];
#pragma unroll
            for (int i = 0; i < 4; i++)
#pragma unroll
                for (int j = 0; j < 4; j++)
                    acc[i][j] = fmaf(av[i], bv[j], acc[i][j]);
        }
        __syncthreads();
    }
    float* obase = Xbuf + ((long)blockIdx.x * BS) * G4 + jt * 64;
#pragma unroll
    for (int i = 0; i < 4; i++) {
        int r = ty * 4 + i;
        float* orow = obase + (long)r * G4;
#pragma unroll
        for (int j = 0; j < 4; j++) {
            int col = tx * 4 + j;
            int gj = jt * 64 + col;
            orow[col] = acc[i][j] + b_ih[gj] + b_hh[gj];
        }
    }
}

// bg-local grid barrier: only the 64 blocks sharing bg (which exchange h)
// participate. Block stores flags[bx] = target (no RMW); wave 0 polls one
// flag per lane; waves 1-3 wait at s_barrier. Targets are absolute step
// numbers -> monotone, no reset race. Group flag region = 256B, line-disjoint.
__device__ __forceinline__ void gbar(int* flags, int bx, int bg, int target) {
    __syncthreads();   // each wave drains its vmcnt before s_barrier (release)
    if (threadIdx.x == 0)
        __hip_atomic_store(&flags[bx], target, __ATOMIC_RELAXED,
                           __HIP_MEMORY_SCOPE_AGENT);
    if (threadIdx.x < 64) {
        int guard = 0;
        while (__hip_atomic_load(&flags[bg * 64 + threadIdx.x], __ATOMIC_RELAXED,
                                 __HIP_MEMORY_SCOPE_AGENT) < target) {
            __builtin_amdgcn_s_sleep(1);
            if (++guard > 2000000) break;   // safety valve: fail loud, not hung
        }
    }
    __syncthreads();
}

// Fused LSTM chunk: nsteps steps from t0 in ONE regular launch.
// grid 256 = 4 b-groups x 64 k-slices, block 256. c carried in registers.
// W_hh slice (32 rows, 64KB) staged in LDS ONCE per launch -> hot loop is
// pure LDS+FMA. h exchanged through device-scope (AGENT) atomics.
__global__ __launch_bounds__(256, 1) void k_steps(
    const float* __restrict__ Xbuf, const float* __restrict__ W_hh,
    float* hs_all, float* c_buf, int* flags, int t0, int nsteps) {
    const int bx = blockIdx.x;
    const int js = bx & 63;     // k-slice: kk base = js*8
    const int bg = bx >> 6;     // b-group
    const int tid = threadIdx.x;
    __shared__ float Wl[32][516];       // W_hh rows for this block (once)
    __shared__ float hl[16][516];       // h[b][k], padded
    __shared__ float g_lds[16][33];
    // LDS total ~99KB -> exactly 1 block/CU (required for barrier capacity)

    long cidx = 0;
    float creg = 0.f;
    if (tid < 128) {
        int bb = tid & 15, kk = tid >> 4;           // kk 0..7
        cidx = (long)(bg * 16 + bb) * HD + js * 8 + kk;
        creg = (t0 > 0) ? c_buf[cidx] : 0.f;
    }

    const int b = tid & 15, jj = tid >> 4;
    const int r0 = jj, r1 = jj + 16;
    const long j0 = (long)(r0 >> 3) * HD + js * 8 + (r0 & 7);
    const long j1 = (long)(r1 >> 3) * HD + js * 8 + (r1 & 7);
    const int bglob = bg * 16 + b;

    // ---- stage this block's 32 W_hh rows into LDS (once per launch) ----
    // 32 rows x 128 float4 = 4096 float4; 16 per thread, coalesced.
#pragma unroll
    for (int m = 0; m < 16; ++m) {
        int flat = m * 256 + tid;           // float4 index
        int rr = flat >> 7;                 // row 0..31
        int c4 = flat & 127;                // float4 col
        long jrow = (long)(rr >> 3) * HD + js * 8 + (rr & 7);
        float4 v = *(const float4*)(W_hh + jrow * HD + c4 * 4);
        *(float4*)&Wl[rr][c4 * 4] = v;
    }
    __syncthreads();

    // prefetch X for the first step (later steps prefetch before the barrier)
    float x0 = Xbuf[(long)bglob * G4 + j0];
    float x1 = Xbuf[(long)bglob * G4 + j1];

    for (int dt = 0; dt < nsteps; ++dt) {
        const int t = t0 + dt;
        float acc0 = 0.f, acc1 = 0.f;
        if (t > 0) {
            const float* hprev = hs_all + (long)(t - 1) * BS * HD + (long)bg * 16 * HD;
            const unsigned long long* hp = (const unsigned long long*)hprev;
            // stage 16b x 512k of h: issue ALL 16 coherent loads into regs
            // first (one latency), then bulk-write LDS.
            unsigned long long tmp[16];
#pragma unroll
            for (int m = 0; m < 16; ++m)
                tmp[m] = __hip_atomic_load(hp + m * 256 + tid, __ATOMIC_RELAXED,
                                           __HIP_MEMORY_SCOPE_AGENT);
#pragma unroll
            for (int m = 0; m < 16; ++m)
                *(float2*)&hl[m][2 * tid] = *(float2*)&tmp[m];
            __syncthreads();
            // hot loop: pure LDS + FMA (identical FMA order to prior rounds)
#pragma unroll 8
            for (int k = 0; k < HD; k += 4) {
                float4 wa = *(const float4*)&Wl[r0][k];
                float4 wb = *(const float4*)&Wl[r1][k];
                float4 hv = *(const float4*)&hl[b][k];
                acc0 = fmaf(hv.x, wa.x, acc0); acc0 = fmaf(hv.y, wa.y, acc0);
                acc0 = fmaf(hv.z, wa.z, acc0); acc0 = fmaf(hv.w, wa.w, acc0);
                acc1 = fmaf(hv.x, wb.x, acc1); acc1 = fmaf(hv.y, wb.y, acc1);
                acc1 = fmaf(hv.z, wb.z, acc1); acc1 = fmaf(hv.w, wb.w, acc1);
            }
        }
        g_lds[b][r0] = x0 + acc0;
        g_lds[b][r1] = x1 + acc1;
        __syncthreads();
        if (tid < 128) {
            int bb = tid & 15, kk = tid >> 4;
            float gi = g_lds[bb][kk];
            float gf = g_lds[bb][8 + kk];
            float gg = g_lds[bb][16 + kk];
            float go = g_lds[bb][24 + kk];
            float iv = sigm_f(gi), fv = sigm_f(gf), gv = tanh_f(gg), ov = sigm_f(go);
            float c_new = fv * creg + iv * gv;
            creg = c_new;
            float h_new = ov * tanh_f(c_new);
            __hip_atomic_store(hs_all + (long)t * BS * HD + cidx, h_new,
                               __ATOMIC_RELAXED, __HIP_MEMORY_SCOPE_AGENT);
        }
        if (dt + 1 < nsteps) {
            // prefetch next step's X before the barrier (hidden under poll)
            const float* Xn = Xbuf + (long)(dt + 1) * BS * G4;
            x0 = Xn[(long)bglob * G4 + j0];
            x1 = Xn[(long)bglob * G4 + j1];
            gbar(flags, bx, bg, t + 1);
        } else {
            __syncthreads();
        }
    }
    if (tid < 128) c_buf[cidx] = creg;
}

// logits[b][v] = hs[b][:] . W_out[v][:] + b_out[v].  grid 786, block 256.
__global__ __launch_bounds__(256) void k_logits(
    const float* __restrict__ hsrow, const float* __restrict__ W_out,
    const float* __restrict__ b_out, float* __restrict__ logits) {
    __shared__ float Ast[32][68];
    __shared__ float Bst[32][68];
    const int v0 = blockIdx.x * 64;
    const int tid = threadIdx.x;
    const int tx = tid & 15, ty = tid >> 4;
    const int lr = tid >> 2;
    const int lc = (tid & 3) * 8;
    int vr = v0 + lr; if (vr > NV - 1) vr = NV - 1;
    const float* arow = hsrow + (long)lr * HD + lc;
    const float* wrow = W_out + (long)vr * HD + lc;
    float acc[4][4] = {};
    for (int k0 = 0; k0 < HD; k0 += 32) {
        float4 a0 = *(const float4*)(arow + k0);
        float4 a1 = *(const float4*)(arow + k0 + 4);
        float4 b0 = *(const float4*)(wrow + k0);
        float4 b1 = *(const float4*)(wrow + k0 + 4);
        Ast[lc + 0][lr] = a0.x; Ast[lc + 1][lr] = a0.y;
        Ast[lc + 2][lr] = a0.z; Ast[lc + 3][lr] = a0.w;
        Ast[lc + 4][lr] = a1.x; Ast[lc + 5][lr] = a1.y;
        Ast[lc + 6][lr] = a1.z; Ast[lc + 7][lr] = a1.w;
        Bst[lc + 0][lr] = b0.x; Bst[lc + 1][lr] = b0.y;
        Bst[lc + 2][lr] = b0.z; Bst[lc + 3][lr] = b0.w;
        Bst[lc + 4][lr] = b1.x; Bst[lc + 5][lr] = b1.y;
        Bst[lc + 6][lr] = b1.z; Bst[lc + 7][lr] = b1.w;
        __syncthreads();
#pragma unroll
        for (int kk = 0; kk < 32; kk++) {
            float av[4], bv[4];
            *(float4*)av = *(const float4*)&Ast[kk][ty * 4];
            *(float4*)bv = *(const float4*)&Bst[kk][tx * 4];
#pragma unroll
            for (int i = 0; i < 4; i++)
#pragma unroll
                for (int j = 0; j < 4; j++)
                    acc[i][j] = fmaf(av[i], bv[j], acc[i][j]);
        }
        __syncthreads();
    }
#pragma unroll
    for (int i = 0; i < 4; i++) {
        int b = ty * 4 + i;
#pragma unroll
        for (int j = 0; j < 4; j++) {
            int v = v0 + tx * 4 + j;
            if (v < NV) logits[(long)b * LS + v] = acc[i][j] + b_out[v];
        }
    }
}

// online logsumexp per batch row. grid 64, block 256.
__global__ __launch_bounds__(256) void k_lse(
    const float* __restrict__ logits, float* __restrict__ lse) {
    const int b = blockIdx.x;
    const float* row = logits + (long)b * LS;
    float m = -1e30f, s = 0.f;
    for (int v = threadIdx.x; v < NV; v += 256) {
        float x = row[v];
        if (x > m) { s = s * __expf(m - x) + 1.f; m = x; }
        else s += __expf(x - m);
    }
    for (int off = 32; off; off >>= 1) {
        float m2 = __shfl_down(m, off);
        float s2 = __shfl_down(s, off);
        float M = fmaxf(m, m2);
        s = s * __expf(m - M) + s2 * __expf(m2 - M);
        m = M;
    }
    __shared__ float ms[4], ss[4];
    int wid = threadIdx.x >> 6, lane = threadIdx.x & 63;
    if (lane == 0) { ms[wid] = m; ss[wid] = s; }
    __syncthreads();
    if (threadIdx.x == 0) {
        m = ms[0]; s = ss[0];
        for (int w = 1; w < 4; w++) {
            float M = fmaxf(m, ms[w]);
            s = s * __expf(m - M) + ss[w] * __expf(ms[w] - M);
            m = M;
        }
        lse[b] = m + __logf(s);
    }
}

__global__ __launch_bounds__(64) void k_loss(
    const float* __restrict__ logits, const float* __restrict__ lse,
    const int* __restrict__ tlines, float* __restrict__ out0) {
    int b = threadIdx.x;
    float v = logits[(long)b * LS + tlines[b]] - lse[b];
    for (int off = 32; off; off >>= 1) v += __shfl_down(v, off);
    if (b == 0) out0[0] = -v * (1.f / 64.f);
}

// partial[tc][h][e] = sum_{t in chunk} exp(ht^T hs_t)[h][e]; also exp_S0.
// grid (64, 4): 8x8 tiles of 64x64 over (h,e), 4 t-chunks of 64. block 256.
__global__ __launch_bounds__(256) void k_attn(
    const float* __restrict__ hs, float* __restrict__ eS0, float* __restrict__ part) {
    __shared__ float Att[64][68];
    __shared__ float Bsm[64][68];
    const int hti = blockIdx.x >> 3, eti = blockIdx.x & 7;
    const int tc = blockIdx.y;
    const int tid = threadIdx.x;
    const int lb = tid >> 2;
    const int lseg = (tid & 3) * 16;
    const float* ht = hs + (long)TE * BS * HD;
    {
        const float* src = ht + (long)lb * HD + hti * 64 + lseg;
#pragma unroll
        for (int m = 0; m < 16; m += 4)
            *(float4*)&Att[lb][lseg + m] = *(const float4*)(src + m);
    }
    const int ti = tid >> 4, tj = tid & 15;
    float ps[4][4] = {};
    for (int dt = 0; dt < 64; dt++) {
        const int t = tc * 64 + dt;
        __syncthreads();
        const float* src = hs + ((long)t * BS + lb) * HD + eti * 64 + lseg;
#pragma unroll
        for (int m = 0; m < 16; m += 4)
            *(float4*)&Bsm[lb][lseg + m] = *(const float4*)(src + m);
        __syncthreads();
        float acc[4][4] = {};
#pragma unroll 4
        for (int b = 0; b < 64; b++) {
            float av[4], bv[4];
            *(float4*)av = *(const float4*)&Att[b][ti * 4];
            *(float4*)bv = *(const float4*)&Bsm[b][tj * 4];
#pragma unroll
            for (int i = 0; i < 4; i++)
#pragma unroll
                for (int j = 0; j < 4; j++)
                    acc[i][j] = fmaf(av[i], bv[j], acc[i][j]);
        }
        const bool first = (tc == 0 && dt == 0);
#pragma unroll
        for (int i = 0; i < 4; i++)
#pragma unroll
            for (int j = 0; j < 4; j++) {
                float e = __expf(acc[i][j]);
                ps[i][j] += e;
                if (first)
                    eS0[(long)(hti * 64 + ti * 4 + i) * HD + eti * 64 + tj * 4 + j] = e;
            }
    }
#pragma unroll
    for (int i = 0; i < 4; i++)
#pragma unroll
        for (int j = 0; j < 4; j++)
            part[(long)tc * 262144 + (long)(hti * 64 + ti * 4 + i) * HD + eti * 64 + tj * 4 + j] = ps[i][j];
}

__global__ __launch_bounds__(256) void k_attn_fin(
    const float* __restrict__ eS0, const float* __restrict__ part,
    float* __restrict__ outat) {
    long i = (long)blockIdx.x * 256 + threadIdx.x;
    float d = part[i] + part[262144 + i] + part[2L * 262144 + i] + part[3L * 262144 + i];
    outat[i] = eS0[i] / d;
}

extern "C" void kernel_launch(void* const* d_in, const int* in_sizes, int n_in,
                              void* d_out, int out_size, void* d_ws, size_t ws_size,
                              hipStream_t stream) {
    (void)in_sizes; (void)n_in; (void)out_size; (void)ws_size;
    const int* input_lines  = (const int*)d_in[0];
    const int* target_lines = (const int*)d_in[1];
    const float* emb_in  = (const float*)d_in[2];
    const float* emb_tgt = (const float*)d_in[3];
    const float* W_ih = (const float*)d_in[4];
    const float* W_hh = (const float*)d_in[5];
    const float* b_ih = (const float*)d_in[6];
    const float* b_hh = (const float*)d_in[7];
    const float* W_out = (const float*)d_in[8];
    const float* b_out = (const float*)d_in[9];
    float* out = (float*)d_out;
    float* ws = (float*)d_ws;

    float* X      = ws;                      // 64*64*2048      = 8388608
    float* hs     = X + 8388608;             // 257*64*512      = 8421376
    float* cbuf   = hs + 8421376;            // 64*512          = 32768
    float* logits = cbuf + 32768;            // 64*50304        = 3219456
    float* lse    = logits + 3219456;        // 64
    float* eS0    = lse + 64;                // 262144
    float* part   = eS0 + 262144;            // 4*262144        = 1048576
    // total ~85.5 MB

    // barrier flags (256 ints) live in the logits region (unused until
    // k_logits, which runs after all k_steps). Zeroed per replay.
    int* flags = (int*)logits;
    hipMemsetAsync(flags, 0, 256 * sizeof(int), stream);

    for (int c = 0; c < 4; ++c) {
        hipLaunchKernelGGL(k_x, dim3(64, 32), dim3(256), 0, stream,
                           input_lines, target_lines, emb_in, emb_tgt,
                           W_ih, b_ih, b_hh, X, c * 64);
        hipLaunchKernelGGL(k_steps, dim3(256), dim3(256), 0, stream,
                           X, W_hh, hs, cbuf, flags, c * 64, 64);
    }
    // decoder step folded in as t = 256 (x from emb_tgt[tgt0])
    hipLaunchKernelGGL(k_x, dim3(1, 32), dim3(256), 0, stream,
                       input_lines, target_lines, emb_in, emb_tgt,
                       W_ih, b_ih, b_hh, X, 256);
    hipLaunchKernelGGL(k_steps, dim3(256), dim3(256), 0, stream,
                       X, W_hh, hs, cbuf, flags, 256, 1);

    hipLaunchKernelGGL(k_logits, dim3(786), dim3(256), 0, stream,
                       hs + (long)255 * BS * HD, W_out, b_out, logits);
    hipLaunchKernelGGL(k_lse, dim3(64), dim3(256), 0, stream, logits, lse);
    hipLaunchKernelGGL(k_loss, dim3(1), dim3(64), 0, stream,
                       logits, lse, target_lines, out);
    hipLaunchKernelGGL(k_attn, dim3(64, 4), dim3(256), 0, stream, hs, eS0, part);
    hipLaunchKernelGGL(k_attn_fin, dim3(1024), dim3(256), 0, stream, eS0, part, out + 1);
}

// Round 6
// 3220.433 us; speedup vs baseline: 2.1326x; 1.0294x over previous
//
#include <hip/hip_runtime.h>
#include <cstdint>

#define NV 50257
#define LS 50304   // padded logits row stride (786*64)
#define HD 512
#define G4 2048
#define BS 64
#define TE 256

typedef float f32x4 __attribute__((ext_vector_type(4)));

__device__ __forceinline__ float sigm_f(float x) {
    x = fminf(fmaxf(x, -30.f), 30.f);
    return 1.f / (1.f + __expf(-x));
}
__device__ __forceinline__ float tanh_f(float x) {
    x = fminf(fmaxf(x, -15.f), 15.f);
    float e = __expf(2.f * x);
    return (e - 1.f) / (e + 1.f);
}

// X[t][b][j] = emb_row(t,b) . W_ih[j][:] + b_ih[j] + b_hh[j]
// grid: (nt, 32), block 256. One M-tile = one t (rows = b 0..63), N-tile = 64 j.
__global__ __launch_bounds__(256) void k_x(
    const int* __restrict__ lines, const int* __restrict__ tlines,
    const float* __restrict__ emb_in, const float* __restrict__ emb_tgt,
    const float* __restrict__ W_ih, const float* __restrict__ b_ih,
    const float* __restrict__ b_hh, float* __restrict__ Xbuf, int t0) {
    __shared__ float Ast[32][68];
    __shared__ float Bst[32][68];
    __shared__ const float* rowp[64];
    const int t = t0 + blockIdx.x;
    const int jt = blockIdx.y;
    const int tid = threadIdx.x;
    if (tid < 64) {
        int idx = (t < TE) ? lines[t * BS + tid] : tlines[tid];
        rowp[tid] = ((t < TE) ? emb_in : emb_tgt) + (long)idx * HD;
    }
    __syncthreads();
    const int tx = tid & 15, ty = tid >> 4;
    const int lr = tid >> 2;            // load row 0..63
    const int lc = (tid & 3) * 8;       // load col base in k-chunk
    const float* wrow = W_ih + (long)(jt * 64 + lr) * HD + lc;
    float acc[4][4] = {};
    for (int k0 = 0; k0 < HD; k0 += 32) {
        const float* ar = rowp[lr] + k0 + lc;
        float4 a0 = *(const float4*)ar;
        float4 a1 = *(const float4*)(ar + 4);
        float4 b0 = *(const float4*)(wrow + k0);
        float4 b1 = *(const float4*)(wrow + k0 + 4);
        Ast[lc + 0][lr] = a0.x; Ast[lc + 1][lr] = a0.y;
        Ast[lc + 2][lr] = a0.z; Ast[lc + 3][lr] = a0.w;
        Ast[lc + 4][lr] = a1.x; Ast[lc + 5][lr] = a1.y;
        Ast[lc + 6][lr] = a1.z; Ast[lc + 7][lr] = a1.w;
        Bst[lc + 0][lr] = b0.x; Bst[lc + 1][lr] = b0.y;
        Bst[lc + 2][lr] = b0.z; Bst[lc + 3][lr] = b0.w;
        Bst[lc + 4][lr] = b1.x; Bst[lc + 5][lr] = b1.y;
        Bst[lc + 6][lr] = b1.z; Bst[lc + 7][lr] = b1.w;
        __syncthreads();
#pragma unroll
        for (int kk = 0; kk < 32; kk++) {
            float av[4], bv[4];
            *(float4*)av = *(const float4*)&Ast[kk][ty * 4];
            *(float4*)bv = *(const float4*)&Bst[kk][tx * 4];
#pragma unroll
            for (int i = 0; i < 4; i++)
#pragma unroll
                for (int j = 0; j < 4; j++)
                    acc[i][j] = fmaf(av[i], bv[j], acc[i][j]);
        }
        __syncthreads();
    }
    float* obase = Xbuf + ((long)blockIdx.x * BS) * G4 + jt * 64;
#pragma unroll
    for (int i = 0; i < 4; i++) {
        int r = ty * 4 + i;
        float* orow = obase + (long)r * G4;
#pragma unroll
        for (int j = 0; j < 4; j++) {
            int col = tx * 4 + j;
            int gj = jt * 64 + col;
            orow[col] = acc[i][j] + b_ih[gj] + b_hh[gj];
        }
    }
}

// bg-local grid barrier: only the 64 blocks sharing bg (which exchange h)
// participate. Block stores flags[bx] = target (no RMW); wave 0 polls one
// flag per lane; waves 1-3 wait at s_barrier. Targets are absolute step
// numbers -> monotone, no reset race. Group flag region = 256B, line-disjoint.
__device__ __forceinline__ void gbar(int* flags, int bx, int bg, int target) {
    __syncthreads();   // each wave drains its vmcnt before s_barrier (release)
    if (threadIdx.x == 0)
        __hip_atomic_store(&flags[bx], target, __ATOMIC_RELAXED,
                           __HIP_MEMORY_SCOPE_AGENT);
    if (threadIdx.x < 64) {
        int guard = 0;
        while (__hip_atomic_load(&flags[bg * 64 + threadIdx.x], __ATOMIC_RELAXED,
                                 __HIP_MEMORY_SCOPE_AGENT) < target) {
            __builtin_amdgcn_s_sleep(1);
            if (++guard > 2000000) break;   // safety valve: fail loud, not hung
        }
    }
    __syncthreads();
}

// Fused LSTM chunk: nsteps steps from t0 in ONE regular launch.
// grid 256 = 4 b-groups x 64 k-slices, block 256. c carried in registers.
// W_hh slice (32 rows, 64KB) staged in LDS ONCE per launch -> hot loop is
// pure LDS+FMA. h exchanged via device-coherent (sc0 sc1) loads/stores;
// the gather is 8 back-to-back global_load_dwordx4 + ONE vmcnt wait
// (atomic loads would serialize: ~16 coherent-point latencies per step).
__global__ __launch_bounds__(256, 1) void k_steps(
    const float* __restrict__ Xbuf, const float* __restrict__ W_hh,
    float* hs_all, float* c_buf, int* flags, int t0, int nsteps) {
    const int bx = blockIdx.x;
    const int js = bx & 63;     // k-slice: kk base = js*8
    const int bg = bx >> 6;     // b-group
    const int tid = threadIdx.x;
    __shared__ float Wl[32][516];       // W_hh rows for this block (once)
    __shared__ float hl[16][516];       // h[b][k], padded
    __shared__ float g_lds[16][33];
    // LDS total ~99KB -> exactly 1 block/CU (required for barrier capacity)

    long cidx = 0;
    float creg = 0.f;
    if (tid < 128) {
        int bb = tid & 15, kk = tid >> 4;           // kk 0..7
        cidx = (long)(bg * 16 + bb) * HD + js * 8 + kk;
        creg = (t0 > 0) ? c_buf[cidx] : 0.f;
    }

    const int b = tid & 15, jj = tid >> 4;
    const int r0 = jj, r1 = jj + 16;
    const long j0 = (long)(r0 >> 3) * HD + js * 8 + (r0 & 7);
    const long j1 = (long)(r1 >> 3) * HD + js * 8 + (r1 & 7);
    const int bglob = bg * 16 + b;

    // ---- stage this block's 32 W_hh rows into LDS (once per launch) ----
    // 32 rows x 128 float4 = 4096 float4; 16 per thread, coalesced.
#pragma unroll
    for (int m = 0; m < 16; ++m) {
        int flat = m * 256 + tid;           // float4 index
        int rr = flat >> 7;                 // row 0..31
        int c4 = flat & 127;                // float4 col
        long jrow = (long)(rr >> 3) * HD + js * 8 + (rr & 7);
        float4 v = *(const float4*)(W_hh + jrow * HD + c4 * 4);
        *(float4*)&Wl[rr][c4 * 4] = v;
    }
    __syncthreads();

    // prefetch X for the first step (later steps prefetch before the barrier)
    float x0 = Xbuf[(long)bglob * G4 + j0];
    float x1 = Xbuf[(long)bglob * G4 + j1];

    for (int dt = 0; dt < nsteps; ++dt) {
        const int t = t0 + dt;
        float acc0 = 0.f, acc1 = 0.f;
        if (t > 0) {
            const float* hprev = hs_all + (long)(t - 1) * BS * HD + (long)bg * 16 * HD;
            // gather 16b x 512k of h: 8 device-coherent dwordx4 loads issued
            // back-to-back (pipelined -> ~1 coherent-point latency), ONE wait.
            f32x4 tv[8];
#pragma unroll
            for (int m = 0; m < 8; ++m) {
                const float* a = hprev + (long)(m * 256 + tid) * 4;
                asm volatile("global_load_dwordx4 %0, %1, off sc0 sc1"
                             : "=v"(tv[m]) : "v"(a) : "memory");
            }
            asm volatile("s_waitcnt vmcnt(0)" ::: "memory");
            __builtin_amdgcn_sched_barrier(0);
#pragma unroll
            for (int m = 0; m < 8; ++m) {
                int f4 = m * 256 + tid;     // float4 index over 16b x 128
                *(f32x4*)&hl[f4 >> 7][(f4 & 127) * 4] = tv[m];
            }
            __syncthreads();
            // hot loop: pure LDS + FMA (identical FMA order to prior rounds)
#pragma unroll 8
            for (int k = 0; k < HD; k += 4) {
                float4 wa = *(const float4*)&Wl[r0][k];
                float4 wb = *(const float4*)&Wl[r1][k];
                float4 hv = *(const float4*)&hl[b][k];
                acc0 = fmaf(hv.x, wa.x, acc0); acc0 = fmaf(hv.y, wa.y, acc0);
                acc0 = fmaf(hv.z, wa.z, acc0); acc0 = fmaf(hv.w, wa.w, acc0);
                acc1 = fmaf(hv.x, wb.x, acc1); acc1 = fmaf(hv.y, wb.y, acc1);
                acc1 = fmaf(hv.z, wb.z, acc1); acc1 = fmaf(hv.w, wb.w, acc1);
            }
        }
        g_lds[b][r0] = x0 + acc0;
        g_lds[b][r1] = x1 + acc1;
        __syncthreads();
        if (tid < 128) {
            int bb = tid & 15, kk = tid >> 4;
            float gi = g_lds[bb][kk];
            float gf = g_lds[bb][8 + kk];
            float gg = g_lds[bb][16 + kk];
            float go = g_lds[bb][24 + kk];
            float iv = sigm_f(gi), fv = sigm_f(gf), gv = tanh_f(gg), ov = sigm_f(go);
            float c_new = fv * creg + iv * gv;
            creg = c_new;
            float h_new = ov * tanh_f(c_new);
            __hip_atomic_store(hs_all + (long)t * BS * HD + cidx, h_new,
                               __ATOMIC_RELAXED, __HIP_MEMORY_SCOPE_AGENT);
        }
        if (dt + 1 < nsteps) {
            // prefetch next step's X before the barrier (hidden under poll)
            const float* Xn = Xbuf + (long)(dt + 1) * BS * G4;
            x0 = Xn[(long)bglob * G4 + j0];
            x1 = Xn[(long)bglob * G4 + j1];
            gbar(flags, bx, bg, t + 1);
        } else {
            __syncthreads();
        }
    }
    if (tid < 128) c_buf[cidx] = creg;
}

// logits[b][v] = hs[b][:] . W_out[v][:] + b_out[v].  grid 786, block 256.
__global__ __launch_bounds__(256) void k_logits(
    const float* __restrict__ hsrow, const float* __restrict__ W_out,
    const float* __restrict__ b_out, float* __restrict__ logits) {
    __shared__ float Ast[32][68];
    __shared__ float Bst[32][68];
    const int v0 = blockIdx.x * 64;
    const int tid = threadIdx.x;
    const int tx = tid & 15, ty = tid >> 4;
    const int lr = tid >> 2;
    const int lc = (tid & 3) * 8;
    int vr = v0 + lr; if (vr > NV - 1) vr = NV - 1;
    const float* arow = hsrow + (long)lr * HD + lc;
    const float* wrow = W_out + (long)vr * HD + lc;
    float acc[4][4] = {};
    for (int k0 = 0; k0 < HD; k0 += 32) {
        float4 a0 = *(const float4*)(arow + k0);
        float4 a1 = *(const float4*)(arow + k0 + 4);
        float4 b0 = *(const float4*)(wrow + k0);
        float4 b1 = *(const float4*)(wrow + k0 + 4);
        Ast[lc + 0][lr] = a0.x; Ast[lc + 1][lr] = a0.y;
        Ast[lc + 2][lr] = a0.z; Ast[lc + 3][lr] = a0.w;
        Ast[lc + 4][lr] = a1.x; Ast[lc + 5][lr] = a1.y;
        Ast[lc + 6][lr] = a1.z; Ast[lc + 7][lr] = a1.w;
        Bst[lc + 0][lr] = b0.x; Bst[lc + 1][lr] = b0.y;
        Bst[lc + 2][lr] = b0.z; Bst[lc + 3][lr] = b0.w;
        Bst[lc + 4][lr] = b1.x; Bst[lc + 5][lr] = b1.y;
        Bst[lc + 6][lr] = b1.z; Bst[lc + 7][lr] = b1.w;
        __syncthreads();
#pragma unroll
        for (int kk = 0; kk < 32; kk++) {
            float av[4], bv[4];
            *(float4*)av = *(const float4*)&Ast[kk][ty * 4];
            *(float4*)bv = *(const float4*)&Bst[kk][tx * 4];
#pragma unroll
            for (int i = 0; i < 4; i++)
#pragma unroll
                for (int j = 0; j < 4; j++)
                    acc[i][j] = fmaf(av[i], bv[j], acc[i][j]);
        }
        __syncthreads();
    }
#pragma unroll
    for (int i = 0; i < 4; i++) {
        int b = ty * 4 + i;
#pragma unroll
        for (int j = 0; j < 4; j++) {
            int v = v0 + tx * 4 + j;
            if (v < NV) logits[(long)b * LS + v] = acc[i][j] + b_out[v];
        }
    }
}

// online logsumexp per batch row. grid 64, block 256.
__global__ __launch_bounds__(256) void k_lse(
    const float* __restrict__ logits, float* __restrict__ lse) {
    const int b = blockIdx.x;
    const float* row = logits + (long)b * LS;
    float m = -1e30f, s = 0.f;
    for (int v = threadIdx.x; v < NV; v += 256) {
        float x = row[v];
        if (x > m) { s = s * __expf(m - x) + 1.f; m = x; }
        else s += __expf(x - m);
    }
    for (int off = 32; off; off >>= 1) {
        float m2 = __shfl_down(m, off);
        float s2 = __shfl_down(s, off);
        float M = fmaxf(m, m2);
        s = s * __expf(m - M) + s2 * __expf(m2 - M);
        m = M;
    }
    __shared__ float ms[4], ss[4];
    int wid = threadIdx.x >> 6, lane = threadIdx.x & 63;
    if (lane == 0) { ms[wid] = m; ss[wid] = s; }
    __syncthreads();
    if (threadIdx.x == 0) {
        m = ms[0]; s = ss[0];
        for (int w = 1; w < 4; w++) {
            float M = fmaxf(m, ms[w]);
            s = s * __expf(m - M) + ss[w] * __expf(ms[w] - M);
            m = M;
        }
        lse[b] = m + __logf(s);
    }
}

__global__ __launch_bounds__(64) void k_loss(
    const float* __restrict__ logits, const float* __restrict__ lse,
    const int* __restrict__ tlines, float* __restrict__ out0) {
    int b = threadIdx.x;
    float v = logits[(long)b * LS + tlines[b]] - lse[b];
    for (int off = 32; off; off >>= 1) v += __shfl_down(v, off);
    if (b == 0) out0[0] = -v * (1.f / 64.f);
}

// partial[tc][h][e] = sum_{t in chunk} exp(ht^T hs_t)[h][e]; also exp_S0.
// grid (64, 4): 8x8 tiles of 64x64 over (h,e), 4 t-chunks of 64. block 256.
__global__ __launch_bounds__(256) void k_attn(
    const float* __restrict__ hs, float* __restrict__ eS0, float* __restrict__ part) {
    __shared__ float Att[64][68];
    __shared__ float Bsm[64][68];
    const int hti = blockIdx.x >> 3, eti = blockIdx.x & 7;
    const int tc = blockIdx.y;
    const int tid = threadIdx.x;
    const int lb = tid >> 2;
    const int lseg = (tid & 3) * 16;
    const float* ht = hs + (long)TE * BS * HD;
    {
        const float* src = ht + (long)lb * HD + hti * 64 + lseg;
#pragma unroll
        for (int m = 0; m < 16; m += 4)
            *(float4*)&Att[lb][lseg + m] = *(const float4*)(src + m);
    }
    const int ti = tid >> 4, tj = tid & 15;
    float ps[4][4] = {};
    for (int dt = 0; dt < 64; dt++) {
        const int t = tc * 64 + dt;
        __syncthreads();
        const float* src = hs + ((long)t * BS + lb) * HD + eti * 64 + lseg;
#pragma unroll
        for (int m = 0; m < 16; m += 4)
            *(float4*)&Bsm[lb][lseg + m] = *(const float4*)(src + m);
        __syncthreads();
        float acc[4][4] = {};
#pragma unroll 4
        for (int b = 0; b < 64; b++) {
            float av[4], bv[4];
            *(float4*)av = *(const float4*)&Att[b][ti * 4];
            *(float4*)bv = *(const float4*)&Bsm[b][tj * 4];
#pragma unroll
            for (int i = 0; i < 4; i++)
#pragma unroll
                for (int j = 0; j < 4; j++)
                    acc[i][j] = fmaf(av[i], bv[j], acc[i][j]);
        }
        const bool first = (tc == 0 && dt == 0);
#pragma unroll
        for (int i = 0; i < 4; i++)
#pragma unroll
            for (int j = 0; j < 4; j++) {
                float e = __expf(acc[i][j]);
                ps[i][j] += e;
                if (first)
                    eS0[(long)(hti * 64 + ti * 4 + i) * HD + eti * 64 + tj * 4 + j] = e;
            }
    }
#pragma unroll
    for (int i = 0; i < 4; i++)
#pragma unroll
        for (int j = 0; j < 4; j++)
            part[(long)tc * 262144 + (long)(hti * 64 + ti * 4 + i) * HD + eti * 64 + tj * 4 + j] = ps[i][j];
}

__global__ __launch_bounds__(256) void k_attn_fin(
    const float* __restrict__ eS0, const float* __restrict__ part,
    float* __restrict__ outat) {
    long i = (long)blockIdx.x * 256 + threadIdx.x;
    float d = part[i] + part[262144 + i] + part[2L * 262144 + i] + part[3L * 262144 + i];
    outat[i] = eS0[i] / d;
}

extern "C" void kernel_launch(void* const* d_in, const int* in_sizes, int n_in,
                              void* d_out, int out_size, void* d_ws, size_t ws_size,
                              hipStream_t stream) {
    (void)in_sizes; (void)n_in; (void)out_size; (void)ws_size;
    const int* input_lines  = (const int*)d_in[0];
    const int* target_lines = (const int*)d_in[1];
    const float* emb_in  = (const float*)d_in[2];
    const float* emb_tgt = (const float*)d_in[3];
    const float* W_ih = (const float*)d_in[4];
    const float* W_hh = (const float*)d_in[5];
    const float* b_ih = (const float*)d_in[6];
    const float* b_hh = (const float*)d_in[7];
    const float* W_out = (const float*)d_in[8];
    const float* b_out = (const float*)d_in[9];
    float* out = (float*)d_out;
    float* ws = (float*)d_ws;

    float* X      = ws;                      // 64*64*2048      = 8388608
    float* hs     = X + 8388608;             // 257*64*512      = 8421376
    float* cbuf   = hs + 8421376;            // 64*512          = 32768
    float* logits = cbuf + 32768;            // 64*50304        = 3219456
    float* lse    = logits + 3219456;        // 64
    float* eS0    = lse + 64;                // 262144
    float* part   = eS0 + 262144;            // 4*262144        = 1048576
    // total ~85.5 MB

    // barrier flags (256 ints) live in the logits region (unused until
    // k_logits, which runs after all k_steps). Zeroed per replay.
    int* flags = (int*)logits;
    hipMemsetAsync(flags, 0, 256 * sizeof(int), stream);

    for (int c = 0; c < 4; ++c) {
        hipLaunchKernelGGL(k_x, dim3(64, 32), dim3(256), 0, stream,
                           input_lines, target_lines, emb_in, emb_tgt,
                           W_ih, b_ih, b_hh, X, c * 64);
        hipLaunchKernelGGL(k_steps, dim3(256), dim3(256), 0, stream,
                           X, W_hh, hs, cbuf, flags, c * 64, 64);
    }
    // decoder step folded in as t = 256 (x from emb_tgt[tgt0])
    hipLaunchKernelGGL(k_x, dim3(1, 32), dim3(256), 0, stream,
                       input_lines, target_lines, emb_in, emb_tgt,
                       W_ih, b_ih, b_hh, X, 256);
    hipLaunchKernelGGL(k_steps, dim3(256), dim3(256), 0, stream,
                       X, W_hh, hs, cbuf, flags, 256, 1);

    hipLaunchKernelGGL(k_logits, dim3(786), dim3(256), 0, stream,
                       hs + (long)255 * BS * HD, W_out, b_out, logits);
    hipLaunchKernelGGL(k_lse, dim3(64), dim3(256), 0, stream, logits, lse);
    hipLaunchKernelGGL(k_loss, dim3(1), dim3(64), 0, stream,
                       logits, lse, target_lines, out);
    hipLaunchKernelGGL(k_attn, dim3(64, 4), dim3(256), 0, stream, hs, eS0, part);
    hipLaunchKernelGGL(k_attn_fin, dim3(1024), dim3(256), 0, stream, eS0, part, out + 1);
}

// Round 7
// 3180.493 us; speedup vs baseline: 2.1593x; 1.0126x over previous
//
#include <hip/hip_runtime.h>
#include <cstdint>

#define NV 50257
#define LS 50304   // padded logits row stride (786*64)
#define HD 512
#define G4 2048
#define BS 64
#define TE 256

typedef float f32x4 __attribute__((ext_vector_type(4)));

__device__ __forceinline__ float sigm_f(float x) {
    x = fminf(fmaxf(x, -30.f), 30.f);
    return 1.f / (1.f + __expf(-x));
}
__device__ __forceinline__ float tanh_f(float x) {
    x = fminf(fmaxf(x, -15.f), 15.f);
    float e = __expf(2.f * x);
    return (e - 1.f) / (e + 1.f);
}

// X[t][b][j] = emb_row(t,b) . W_ih[j][:] + b_ih[j] + b_hh[j]
// grid: (nt, 32), block 256. One M-tile = one t (rows = b 0..63), N-tile = 64 j.
__global__ __launch_bounds__(256) void k_x(
    const int* __restrict__ lines, const int* __restrict__ tlines,
    const float* __restrict__ emb_in, const float* __restrict__ emb_tgt,
    const float* __restrict__ W_ih, const float* __restrict__ b_ih,
    const float* __restrict__ b_hh, float* __restrict__ Xbuf, int t0) {
    __shared__ float Ast[32][68];
    __shared__ float Bst[32][68];
    __shared__ const float* rowp[64];
    const int t = t0 + blockIdx.x;
    const int jt = blockIdx.y;
    const int tid = threadIdx.x;
    if (tid < 64) {
        int idx = (t < TE) ? lines[t * BS + tid] : tlines[tid];
        rowp[tid] = ((t < TE) ? emb_in : emb_tgt) + (long)idx * HD;
    }
    __syncthreads();
    const int tx = tid & 15, ty = tid >> 4;
    const int lr = tid >> 2;            // load row 0..63
    const int lc = (tid & 3) * 8;       // load col base in k-chunk
    const float* wrow = W_ih + (long)(jt * 64 + lr) * HD + lc;
    float acc[4][4] = {};
    for (int k0 = 0; k0 < HD; k0 += 32) {
        const float* ar = rowp[lr] + k0 + lc;
        float4 a0 = *(const float4*)ar;
        float4 a1 = *(const float4*)(ar + 4);
        float4 b0 = *(const float4*)(wrow + k0);
        float4 b1 = *(const float4*)(wrow + k0 + 4);
        Ast[lc + 0][lr] = a0.x; Ast[lc + 1][lr] = a0.y;
        Ast[lc + 2][lr] = a0.z; Ast[lc + 3][lr] = a0.w;
        Ast[lc + 4][lr] = a1.x; Ast[lc + 5][lr] = a1.y;
        Ast[lc + 6][lr] = a1.z; Ast[lc + 7][lr] = a1.w;
        Bst[lc + 0][lr] = b0.x; Bst[lc + 1][lr] = b0.y;
        Bst[lc + 2][lr] = b0.z; Bst[lc + 3][lr] = b0.w;
        Bst[lc + 4][lr] = b1.x; Bst[lc + 5][lr] = b1.y;
        Bst[lc + 6][lr] = b1.z; Bst[lc + 7][lr] = b1.w;
        __syncthreads();
#pragma unroll
        for (int kk = 0; kk < 32; kk++) {
            float av[4], bv[4];
            *(float4*)av = *(const float4*)&Ast[kk][ty * 4];
            *(float4*)bv = *(const float4*)&Bst[kk][tx * 4];
#pragma unroll
            for (int i = 0; i < 4; i++)
#pragma unroll
                for (int j = 0; j < 4; j++)
                    acc[i][j] = fmaf(av[i], bv[j], acc[i][j]);
        }
        __syncthreads();
    }
    float* obase = Xbuf + ((long)blockIdx.x * BS) * G4 + jt * 64;
#pragma unroll
    for (int i = 0; i < 4; i++) {
        int r = ty * 4 + i;
        float* orow = obase + (long)r * G4;
#pragma unroll
        for (int j = 0; j < 4; j++) {
            int col = tx * 4 + j;
            int gj = jt * 64 + col;
            orow[col] = acc[i][j] + b_ih[gj] + b_hh[gj];
        }
    }
}

// bg-local grid barrier: only the 64 blocks sharing bg (which exchange h)
// participate. Block stores flags[bx] = target (no RMW); wave 0 polls one
// flag per lane; waves 1-3 wait at s_barrier. Targets are absolute step
// numbers -> monotone, no reset race. Group flag region = 256B, line-disjoint.
__device__ __forceinline__ void gbar(int* flags, int bx, int bg, int target) {
    __syncthreads();   // each wave drains its vmcnt before s_barrier (release)
    if (threadIdx.x == 0)
        __hip_atomic_store(&flags[bx], target, __ATOMIC_RELAXED,
                           __HIP_MEMORY_SCOPE_AGENT);
    if (threadIdx.x < 64) {
        int guard = 0;
        while (__hip_atomic_load(&flags[bg * 64 + threadIdx.x], __ATOMIC_RELAXED,
                                 __HIP_MEMORY_SCOPE_AGENT) < target) {
            __builtin_amdgcn_s_sleep(1);
            if (++guard > 2000000) break;   // safety valve: fail loud, not hung
        }
    }
    __syncthreads();
}

// Fused LSTM chunk: nsteps steps from t0 in ONE regular launch.
// grid 256 = 4 b-groups x 64 k-slices, block 256.
// NEW: W_hh lives in REGISTERS (thread (r2,bh,ks) holds 2 rows x 64-float
// k-segment = 128 VGPR), split-k over 8 lanes + shuffle-tree reduction.
// LDS read traffic per step drops 3x (384 -> 128 b128/thread).
// h staged in LDS with slot swizzle ((i+ks)&15) -> conflict-free reads.
__global__ __launch_bounds__(256, 1) void k_steps(
    const float* __restrict__ Xbuf, const float* __restrict__ W_hh,
    float* hs_all, float* c_buf, int* flags, int t0, int nsteps) {
    const int bx = blockIdx.x;
    const int js = bx & 63;     // k-slice of gate rows: 8 per gate
    const int bg = bx >> 6;     // b-group (16 batches)
    const int tid = threadIdx.x;
    __shared__ float hl[16][516];       // h[b][k] (swizzled 64-float segments)
    __shared__ float g_lds[16][33];
    __shared__ float lds_pad[16384];    // 64KB pad -> force 1 block/CU
    if (nsteps == -1) ((volatile float*)lds_pad)[tid] = (float)t0; // keep alive

    long cidx = 0;
    float creg = 0.f;
    if (tid < 128) {
        int bb = tid & 15, kk = tid >> 4;           // kk 0..7
        cidx = (long)(bg * 16 + bb) * HD + js * 8 + kk;
        creg = (t0 > 0) ? c_buf[cidx] : 0.f;
    }

    const int ks = tid & 7;           // k-segment 0..7 (64 floats)
    const int bh = (tid >> 3) & 1;    // batch half
    const int r2 = tid >> 4;          // row-pair 0..15
    const int ra = 2 * r2, rb = 2 * r2 + 1;
    const long ja = (long)(ra >> 3) * HD + js * 8 + (ra & 7);
    const long jb = (long)(rb >> 3) * HD + js * 8 + (rb & 7);

    // ---- W_hh into registers: 2 rows x 64 floats (once per launch) ----
    f32x4 wA[16], wB[16];
#pragma unroll
    for (int i = 0; i < 16; ++i) {
        wA[i] = *(const f32x4*)(W_hh + ja * HD + 64 * ks + 4 * i);
        wB[i] = *(const f32x4*)(W_hh + jb * HD + 64 * ks + 4 * i);
    }
    // swizzled slot offsets (float units) for this thread's k-segment
    int sl[16];
#pragma unroll
    for (int i = 0; i < 16; ++i) sl[i] = 64 * ks + 4 * ((i + ks) & 15);

    const int bwr = bh * 8 + ks;                 // batch this thread finalizes
    const int bglob = bg * 16 + bwr;

    // prefetch X for the first step (later steps prefetch before the barrier)
    float x0 = Xbuf[(long)bglob * G4 + ja];
    float x1 = Xbuf[(long)bglob * G4 + jb];

    for (int dt = 0; dt < nsteps; ++dt) {
        const int t = t0 + dt;
        float pa[8] = {0.f,0.f,0.f,0.f,0.f,0.f,0.f,0.f};
        float pb[8] = {0.f,0.f,0.f,0.f,0.f,0.f,0.f,0.f};
        if (t > 0) {
            const float* hprev = hs_all + (long)(t - 1) * BS * HD + (long)bg * 16 * HD;
            // gather 16b x 512k of h: 8 device-coherent dwordx4, ONE wait
            f32x4 tv[8];
#pragma unroll
            for (int m = 0; m < 8; ++m) {
                const float* a = hprev + (long)(m * 256 + tid) * 4;
                asm volatile("global_load_dwordx4 %0, %1, off sc0 sc1"
                             : "=v"(tv[m]) : "v"(a) : "memory");
            }
            asm volatile("s_waitcnt vmcnt(0)" ::: "memory");
            __builtin_amdgcn_sched_barrier(0);
            // scatter into swizzled LDS layout
#pragma unroll
            for (int m = 0; m < 8; ++m) {
                int f4 = m * 256 + tid;          // float4 idx over [16][128]
                int bb_ = f4 >> 7;
                int c4 = f4 & 127;
                int ksw = c4 >> 4, iw = c4 & 15;
                *(f32x4*)&hl[bb_][64 * ksw + 4 * ((iw + ksw) & 15)] = tv[m];
            }
            __syncthreads();
            // register-W GEMM: 128 ds_read_b128 + 1024 FMA per thread
            const float* h0 = &hl[8 * bh][0];
#pragma unroll
            for (int i = 0; i < 16; ++i) {
                f32x4 hv[8];
#pragma unroll
                for (int bi = 0; bi < 8; ++bi)
                    hv[bi] = *(const f32x4*)(h0 + bi * 516 + sl[i]);
#pragma unroll
                for (int bi = 0; bi < 8; ++bi) {
                    pa[bi] = fmaf(hv[bi].x, wA[i].x, pa[bi]);
                    pa[bi] = fmaf(hv[bi].y, wA[i].y, pa[bi]);
                    pa[bi] = fmaf(hv[bi].z, wA[i].z, pa[bi]);
                    pa[bi] = fmaf(hv[bi].w, wA[i].w, pa[bi]);
                    pb[bi] = fmaf(hv[bi].x, wB[i].x, pb[bi]);
                    pb[bi] = fmaf(hv[bi].y, wB[i].y, pb[bi]);
                    pb[bi] = fmaf(hv[bi].z, wB[i].z, pb[bi]);
                    pb[bi] = fmaf(hv[bi].w, wB[i].w, pb[bi]);
                }
            }
            // split-k tree reduction over the 8 ks-lanes (butterfly)
#pragma unroll
            for (int bi = 0; bi < 8; ++bi) {
                pa[bi] += __shfl_xor(pa[bi], 1);
                pa[bi] += __shfl_xor(pa[bi], 2);
                pa[bi] += __shfl_xor(pa[bi], 4);
                pb[bi] += __shfl_xor(pb[bi], 1);
                pb[bi] += __shfl_xor(pb[bi], 2);
                pb[bi] += __shfl_xor(pb[bi], 4);
            }
        }
        // each lane finalizes batch bwr = bh*8+ks: select pa[ks] (unrolled)
        float va = pa[0], vb = pb[0];
#pragma unroll
        for (int j = 1; j < 8; ++j)
            if (ks == j) { va = pa[j]; vb = pb[j]; }
        g_lds[bwr][ra] = va + x0;
        g_lds[bwr][rb] = vb + x1;
        __syncthreads();
        if (tid < 128) {
            int bb = tid & 15, kk = tid >> 4;
            float gi = g_lds[bb][kk];
            float gf = g_lds[bb][8 + kk];
            float gg = g_lds[bb][16 + kk];
            float go = g_lds[bb][24 + kk];
            float iv = sigm_f(gi), fv = sigm_f(gf), gv = tanh_f(gg), ov = sigm_f(go);
            float c_new = fv * creg + iv * gv;
            creg = c_new;
            float h_new = ov * tanh_f(c_new);
            __hip_atomic_store(hs_all + (long)t * BS * HD + cidx, h_new,
                               __ATOMIC_RELAXED, __HIP_MEMORY_SCOPE_AGENT);
        }
        if (dt + 1 < nsteps) {
            // prefetch next step's X before the barrier (hidden under poll)
            const float* Xn = Xbuf + (long)(dt + 1) * BS * G4;
            x0 = Xn[(long)bglob * G4 + ja];
            x1 = Xn[(long)bglob * G4 + jb];
            gbar(flags, bx, bg, t + 1);
        } else {
            __syncthreads();
        }
    }
    if (tid < 128) c_buf[cidx] = creg;
}

// logits[b][v] = hs[b][:] . W_out[v][:] + b_out[v].  grid 786, block 256.
__global__ __launch_bounds__(256) void k_logits(
    const float* __restrict__ hsrow, const float* __restrict__ W_out,
    const float* __restrict__ b_out, float* __restrict__ logits) {
    __shared__ float Ast[32][68];
    __shared__ float Bst[32][68];
    const int v0 = blockIdx.x * 64;
    const int tid = threadIdx.x;
    const int tx = tid & 15, ty = tid >> 4;
    const int lr = tid >> 2;
    const int lc = (tid & 3) * 8;
    int vr = v0 + lr; if (vr > NV - 1) vr = NV - 1;
    const float* arow = hsrow + (long)lr * HD + lc;
    const float* wrow = W_out + (long)vr * HD + lc;
    float acc[4][4] = {};
    for (int k0 = 0; k0 < HD; k0 += 32) {
        float4 a0 = *(const float4*)(arow + k0);
        float4 a1 = *(const float4*)(arow + k0 + 4);
        float4 b0 = *(const float4*)(wrow + k0);
        float4 b1 = *(const float4*)(wrow + k0 + 4);
        Ast[lc + 0][lr] = a0.x; Ast[lc + 1][lr] = a0.y;
        Ast[lc + 2][lr] = a0.z; Ast[lc + 3][lr] = a0.w;
        Ast[lc + 4][lr] = a1.x; Ast[lc + 5][lr] = a1.y;
        Ast[lc + 6][lr] = a1.z; Ast[lc + 7][lr] = a1.w;
        Bst[lc + 0][lr] = b0.x; Bst[lc + 1][lr] = b0.y;
        Bst[lc + 2][lr] = b0.z; Bst[lc + 3][lr] = b0.w;
        Bst[lc + 4][lr] = b1.x; Bst[lc + 5][lr] = b1.y;
        Bst[lc + 6][lr] = b1.z; Bst[lc + 7][lr] = b1.w;
        __syncthreads();
#pragma unroll
        for (int kk = 0; kk < 32; kk++) {
            float av[4], bv[4];
            *(float4*)av = *(const float4*)&Ast[kk][ty * 4];
            *(float4*)bv = *(const float4*)&Bst[kk][tx * 4];
#pragma unroll
            for (int i = 0; i < 4; i++)
#pragma unroll
                for (int j = 0; j < 4; j++)
                    acc[i][j] = fmaf(av[i], bv[j], acc[i][j]);
        }
        __syncthreads();
    }
#pragma unroll
    for (int i = 0; i < 4; i++) {
        int b = ty * 4 + i;
#pragma unroll
        for (int j = 0; j < 4; j++) {
            int v = v0 + tx * 4 + j;
            if (v < NV) logits[(long)b * LS + v] = acc[i][j] + b_out[v];
        }
    }
}

// online logsumexp per batch row. grid 64, block 256.
__global__ __launch_bounds__(256) void k_lse(
    const float* __restrict__ logits, float* __restrict__ lse) {
    const int b = blockIdx.x;
    const float* row = logits + (long)b * LS;
    float m = -1e30f, s = 0.f;
    for (int v = threadIdx.x; v < NV; v += 256) {
        float x = row[v];
        if (x > m) { s = s * __expf(m - x) + 1.f; m = x; }
        else s += __expf(x - m);
    }
    for (int off = 32; off; off >>= 1) {
        float m2 = __shfl_down(m, off);
        float s2 = __shfl_down(s, off);
        float M = fmaxf(m, m2);
        s = s * __expf(m - M) + s2 * __expf(m2 - M);
        m = M;
    }
    __shared__ float ms[4], ss[4];
    int wid = threadIdx.x >> 6, lane = threadIdx.x & 63;
    if (lane == 0) { ms[wid] = m; ss[wid] = s; }
    __syncthreads();
    if (threadIdx.x == 0) {
        m = ms[0]; s = ss[0];
        for (int w = 1; w < 4; w++) {
            float M = fmaxf(m, ms[w]);
            s = s * __expf(m - M) + ss[w] * __expf(ms[w] - M);
            m = M;
        }
        lse[b] = m + __logf(s);
    }
}

__global__ __launch_bounds__(64) void k_loss(
    const float* __restrict__ logits, const float* __restrict__ lse,
    const int* __restrict__ tlines, float* __restrict__ out0) {
    int b = threadIdx.x;
    float v = logits[(long)b * LS + tlines[b]] - lse[b];
    for (int off = 32; off; off >>= 1) v += __shfl_down(v, off);
    if (b == 0) out0[0] = -v * (1.f / 64.f);
}

// partial[tc][h][e] = sum_{t in chunk} exp(ht^T hs_t)[h][e]; also exp_S0.
// grid (64, 4): 8x8 tiles of 64x64 over (h,e), 4 t-chunks of 64. block 256.
__global__ __launch_bounds__(256) void k_attn(
    const float* __restrict__ hs, float* __restrict__ eS0, float* __restrict__ part) {
    __shared__ float Att[64][68];
    __shared__ float Bsm[64][68];
    const int hti = blockIdx.x >> 3, eti = blockIdx.x & 7;
    const int tc = blockIdx.y;
    const int tid = threadIdx.x;
    const int lb = tid >> 2;
    const int lseg = (tid & 3) * 16;
    const float* ht = hs + (long)TE * BS * HD;
    {
        const float* src = ht + (long)lb * HD + hti * 64 + lseg;
#pragma unroll
        for (int m = 0; m < 16; m += 4)
            *(float4*)&Att[lb][lseg + m] = *(const float4*)(src + m);
    }
    const int ti = tid >> 4, tj = tid & 15;
    float ps[4][4] = {};
    for (int dt = 0; dt < 64; dt++) {
        const int t = tc * 64 + dt;
        __syncthreads();
        const float* src = hs + ((long)t * BS + lb) * HD + eti * 64 + lseg;
#pragma unroll
        for (int m = 0; m < 16; m += 4)
            *(float4*)&Bsm[lb][lseg + m] = *(const float4*)(src + m);
        __syncthreads();
        float acc[4][4] = {};
#pragma unroll 4
        for (int b = 0; b < 64; b++) {
            float av[4], bv[4];
            *(float4*)av = *(const float4*)&Att[b][ti * 4];
            *(float4*)bv = *(const float4*)&Bsm[b][tj * 4];
#pragma unroll
            for (int i = 0; i < 4; i++)
#pragma unroll
                for (int j = 0; j < 4; j++)
                    acc[i][j] = fmaf(av[i], bv[j], acc[i][j]);
        }
        const bool first = (tc == 0 && dt == 0);
#pragma unroll
        for (int i = 0; i < 4; i++)
#pragma unroll
            for (int j = 0; j < 4; j++) {
                float e = __expf(acc[i][j]);
                ps[i][j] += e;
                if (first)
                    eS0[(long)(hti * 64 + ti * 4 + i) * HD + eti * 64 + tj * 4 + j] = e;
            }
    }
#pragma unroll
    for (int i = 0; i < 4; i++)
#pragma unroll
        for (int j = 0; j < 4; j++)
            part[(long)tc * 262144 + (long)(hti * 64 + ti * 4 + i) * HD + eti * 64 + tj * 4 + j] = ps[i][j];
}

__global__ __launch_bounds__(256) void k_attn_fin(
    const float* __restrict__ eS0, const float* __restrict__ part,
    float* __restrict__ outat) {
    long i = (long)blockIdx.x * 256 + threadIdx.x;
    float d = part[i] + part[262144 + i] + part[2L * 262144 + i] + part[3L * 262144 + i];
    outat[i] = eS0[i] / d;
}

extern "C" void kernel_launch(void* const* d_in, const int* in_sizes, int n_in,
                              void* d_out, int out_size, void* d_ws, size_t ws_size,
                              hipStream_t stream) {
    (void)in_sizes; (void)n_in; (void)out_size; (void)ws_size;
    const int* input_lines  = (const int*)d_in[0];
    const int* target_lines = (const int*)d_in[1];
    const float* emb_in  = (const float*)d_in[2];
    const float* emb_tgt = (const float*)d_in[3];
    const float* W_ih = (const float*)d_in[4];
    const float* W_hh = (const float*)d_in[5];
    const float* b_ih = (const float*)d_in[6];
    const float* b_hh = (const float*)d_in[7];
    const float* W_out = (const float*)d_in[8];
    const float* b_out = (const float*)d_in[9];
    float* out = (float*)d_out;
    float* ws = (float*)d_ws;

    float* X      = ws;                      // 64*64*2048      = 8388608
    float* hs     = X + 8388608;             // 257*64*512      = 8421376
    float* cbuf   = hs + 8421376;            // 64*512          = 32768
    float* logits = cbuf + 32768;            // 64*50304        = 3219456
    float* lse    = logits + 3219456;        // 64
    float* eS0    = lse + 64;                // 262144
    float* part   = eS0 + 262144;            // 4*262144        = 1048576
    // total ~85.5 MB

    // barrier flags (256 ints) live in the logits region (unused until
    // k_logits, which runs after all k_steps). Zeroed per replay.
    int* flags = (int*)logits;
    hipMemsetAsync(flags, 0, 256 * sizeof(int), stream);

    for (int c = 0; c < 4; ++c) {
        hipLaunchKernelGGL(k_x, dim3(64, 32), dim3(256), 0, stream,
                           input_lines, target_lines, emb_in, emb_tgt,
                           W_ih, b_ih, b_hh, X, c * 64);
        hipLaunchKernelGGL(k_steps, dim3(256), dim3(256), 0, stream,
                           X, W_hh, hs, cbuf, flags, c * 64, 64);
    }
    // decoder step folded in as t = 256 (x from emb_tgt[tgt0])
    hipLaunchKernelGGL(k_x, dim3(1, 32), dim3(256), 0, stream,
                       input_lines, target_lines, emb_in, emb_tgt,
                       W_ih, b_ih, b_hh, X, 256);
    hipLaunchKernelGGL(k_steps, dim3(256), dim3(256), 0, stream,
                       X, W_hh, hs, cbuf, flags, 256, 1);

    hipLaunchKernelGGL(k_logits, dim3(786), dim3(256), 0, stream,
                       hs + (long)255 * BS * HD, W_out, b_out, logits);
    hipLaunchKernelGGL(k_lse, dim3(64), dim3(256), 0, stream, logits, lse);
    hipLaunchKernelGGL(k_loss, dim3(1), dim3(64), 0, stream,
                       logits, lse, target_lines, out);
    hipLaunchKernelGGL(k_attn, dim3(64, 4), dim3(256), 0, stream, hs, eS0, part);
    hipLaunchKernelGGL(k_attn_fin, dim3(1024), dim3(256), 0, stream, eS0, part, out + 1);
}